// Round 1
// baseline (910.304 us; speedup 1.0000x reference)
//
#include <hip/hip_runtime.h>
#include <hip/hip_bf16.h>

#define THREADS 256

// ---------- CSR build ----------
__global__ void k_init(float* deg_s, float* deg_f, int* cnt_s, int* cnt_f, int N) {
  for (int i = blockIdx.x * blockDim.x + threadIdx.x; i < N; i += gridDim.x * blockDim.x) {
    deg_s[i] = 1.0f; deg_f[i] = 1.0f;   // self-loop weight 1
    cnt_s[i] = 0;    cnt_f[i] = 0;
  }
}

__global__ void k_count(const int* __restrict__ col, const float* __restrict__ w,
                        float* deg, int* cnt, int E) {
  int e = blockIdx.x * blockDim.x + threadIdx.x;
  if (e < E) {
    int c = col[e];
    atomicAdd(&cnt[c], 1);
    atomicAdd(&deg[c], w[e]);
  }
}

// block 0 scans graph-sc, block 1 scans graph-fc. cnt is rewritten with the
// exclusive scan (doubles as the scatter cursor); rp gets the rowptr.
__global__ void k_scan(int* cnt_s, int* rp_s, int* cnt_f, int* rp_f, int N) {
  int* cnt = (blockIdx.x == 0) ? cnt_s : cnt_f;
  int* rp  = (blockIdx.x == 0) ? rp_s  : rp_f;
  __shared__ int buf[THREADS];
  __shared__ int carry;
  if (threadIdx.x == 0) carry = 0;
  __syncthreads();
  for (int base = 0; base < N; base += THREADS) {
    int i = base + threadIdx.x;
    int v = (i < N) ? cnt[i] : 0;
    buf[threadIdx.x] = v;
    __syncthreads();
    #pragma unroll
    for (int off = 1; off < THREADS; off <<= 1) {
      int t = (threadIdx.x >= off) ? buf[threadIdx.x - off] : 0;
      __syncthreads();
      buf[threadIdx.x] += t;
      __syncthreads();
    }
    if (i < N) {
      int excl = carry + buf[threadIdx.x] - v;
      rp[i]  = excl;
      cnt[i] = excl;  // cursor init
    }
    __syncthreads();
    if (threadIdx.x == 0) carry += buf[THREADS - 1];
    __syncthreads();
  }
  if (threadIdx.x == 0) rp[N] = carry;
}

__global__ void k_dis(float* deg_s, float* deg_f, int N) {  // deg -> rsqrt(deg), in place
  for (int i = blockIdx.x * blockDim.x + threadIdx.x; i < N; i += gridDim.x * blockDim.x) {
    deg_s[i] = rsqrtf(deg_s[i]);
    deg_f[i] = rsqrtf(deg_f[i]);
  }
}

__global__ void k_scatter(const int* __restrict__ ei, const float* __restrict__ w,
                          const float* __restrict__ dis, int* cur,
                          int* __restrict__ src, float* __restrict__ nw, int E) {
  int e = blockIdx.x * blockDim.x + threadIdx.x;
  if (e < E) {
    int r = ei[e];
    int c = ei[E + e];
    int pos = atomicAdd(&cur[c], 1);
    src[pos] = r;
    nw[pos]  = dis[r] * w[e] * dis[c];
  }
}

// ---------- GEMM: C = A(N x 128) @ B(128 x 128), both branches via blockIdx.y ----------
__global__ __launch_bounds__(THREADS) void k_gemm(const float* __restrict__ A,
                                                  const float* __restrict__ B0,
                                                  const float* __restrict__ B1,
                                                  float* __restrict__ C0,
                                                  float* __restrict__ C1, int N) {
  const float* B = blockIdx.y ? B1 : B0;
  float*       C = blockIdx.y ? C1 : C0;
  __shared__ float Bs[128 * 128];   // 64 KiB
  int tid = threadIdx.x;
  #pragma unroll
  for (int i = 0; i < 16; ++i) {
    int idx = (i * THREADS + tid) * 4;
    *(float4*)&Bs[idx] = *(const float4*)&B[idx];
  }
  __syncthreads();

  int tr = tid >> 5;   // 0..7  -> 4 rows each
  int tc = tid & 31;   // 0..31 -> 4 cols each
  int r0 = blockIdx.x * 32;
  if (r0 >= N) return;
  int rbase = r0 + tr * 4;

  const float* ap[4];
  #pragma unroll
  for (int i = 0; i < 4; ++i) {
    int r = rbase + i; if (r > N - 1) r = N - 1;   // clamp; store is guarded
    ap[i] = A + (size_t)r * 128;
  }

  float acc[4][4] = {};
  for (int k4 = 0; k4 < 128; k4 += 4) {
    float4 a[4], b[4];
    #pragma unroll
    for (int i = 0; i < 4; ++i) a[i] = *(const float4*)(ap[i] + k4);
    #pragma unroll
    for (int kk = 0; kk < 4; ++kk) b[kk] = *(const float4*)&Bs[(k4 + kk) * 128 + tc * 4];
    #pragma unroll
    for (int i = 0; i < 4; ++i) {
      const float* av = (const float*)&a[i];
      #pragma unroll
      for (int kk = 0; kk < 4; ++kk) {
        acc[i][0] = fmaf(av[kk], b[kk].x, acc[i][0]);
        acc[i][1] = fmaf(av[kk], b[kk].y, acc[i][1]);
        acc[i][2] = fmaf(av[kk], b[kk].z, acc[i][2]);
        acc[i][3] = fmaf(av[kk], b[kk].w, acc[i][3]);
      }
    }
  }
  #pragma unroll
  for (int i = 0; i < 4; ++i) {
    int r = rbase + i;
    if (r < N)
      *(float4*)&C[(size_t)r * 128 + tc * 4] =
          make_float4(acc[i][0], acc[i][1], acc[i][2], acc[i][3]);
  }
}

// ---------- aggregation: agg[v] = t_sc[v]/deg_s + t_fc[v]/deg_f + sum_in-edges ----------
__global__ __launch_bounds__(THREADS) void k_gather(
    const float* __restrict__ t_sc, const float* __restrict__ t_fc,
    const int* __restrict__ rp_s, const int* __restrict__ src_s, const float* __restrict__ nw_s,
    const int* __restrict__ rp_f, const int* __restrict__ src_f, const float* __restrict__ nw_f,
    const float* __restrict__ dis_s, const float* __restrict__ dis_f,
    float* __restrict__ agg, int N) {
  int gw     = (blockIdx.x * blockDim.x + threadIdx.x) >> 6;
  int lane   = threadIdx.x & 63;
  int nwaves = (gridDim.x * blockDim.x) >> 6;
  for (int v = gw; v < N; v += nwaves) {
    float ds = dis_s[v], df = dis_f[v];
    float inv_s = ds * ds, inv_f = df * df;   // self-loop norm = 1/deg
    float2 a = ((const float2*)(t_sc + (size_t)v * 128))[lane];
    float2 b = ((const float2*)(t_fc + (size_t)v * 128))[lane];
    float ax = a.x * inv_s + b.x * inv_f;
    float ay = a.y * inv_s + b.y * inv_f;
    int e0 = rp_s[v], e1 = rp_s[v + 1];
    for (int e = e0; e < e1; ++e) {
      int s = src_s[e]; float w = nw_s[e];
      float2 tv = ((const float2*)(t_sc + (size_t)s * 128))[lane];
      ax = fmaf(tv.x, w, ax); ay = fmaf(tv.y, w, ay);
    }
    e0 = rp_f[v]; e1 = rp_f[v + 1];
    for (int e = e0; e < e1; ++e) {
      int s = src_f[e]; float w = nw_f[e];
      float2 tv = ((const float2*)(t_fc + (size_t)s * 128))[lane];
      ax = fmaf(tv.x, w, ax); ay = fmaf(tv.y, w, ay);
    }
    ((float2*)(agg + (size_t)v * 128))[lane] = make_float2(ax, ay);
  }
}

// ---------- BN stats + apply ----------
__global__ void k_zero_stats(double* stats) { stats[threadIdx.x] = 0.0; }

__global__ void k_stats(const float* __restrict__ agg, double* stats, int N) {
  __shared__ double sb[THREADS], qb[THREADS];
  int col  = threadIdx.x & 127;
  int half = threadIdx.x >> 7;
  double s = 0, q = 0;
  for (int r = blockIdx.x * 2 + half; r < N; r += gridDim.x * 2) {
    float v = agg[(size_t)r * 128 + col];
    s += v; q += (double)v * v;
  }
  sb[threadIdx.x] = s; qb[threadIdx.x] = q;
  __syncthreads();
  if (half == 0) {
    atomicAdd(&stats[col],       sb[threadIdx.x] + sb[threadIdx.x + 128]);
    atomicAdd(&stats[128 + col], qb[threadIdx.x] + qb[threadIdx.x + 128]);
  }
}

__global__ void k_bn(const float* __restrict__ agg, const double* __restrict__ stats,
                     const float* __restrict__ gamma, const float* __restrict__ beta,
                     float* __restrict__ out, int N) {
  int total = N * 128;
  double invN = 1.0 / (double)N;
  for (int i = blockIdx.x * blockDim.x + threadIdx.x; i < total; i += gridDim.x * blockDim.x) {
    int c = i & 127;
    double m   = stats[c] * invN;
    double var = stats[128 + c] * invN - m * m;
    float scale = gamma[c] * rsqrtf((float)var + 1e-5f);
    float shift = beta[c] - (float)m * scale;
    float v = fmaf(agg[i], scale, shift);
    out[i] = v > 0.f ? v : 0.f;
  }
}

extern "C" void kernel_launch(void* const* d_in, const int* in_sizes, int n_in,
                              void* d_out, int out_size, void* d_ws, size_t ws_size,
                              hipStream_t stream) {
  const float* x     = (const float*)d_in[0];
  const int*   ei_s  = (const int*)d_in[1];
  const float* w_s   = (const float*)d_in[2];
  const int*   ei_f  = (const int*)d_in[3];
  const float* w_f   = (const float*)d_in[4];
  const float* W_s   = (const float*)d_in[5];
  const float* W_f   = (const float*)d_in[7];
  const float* gamma = (const float*)d_in[9];
  const float* beta  = (const float*)d_in[10];
  float* out = (float*)d_out;

  const int N = in_sizes[0] / 128;
  const int E = in_sizes[2];
  const int L = in_sizes[5] / (128 * 128);

  char* ws = (char*)d_ws;
  size_t off = 0;
  auto alloc = [&](size_t bytes) -> void* {
    void* p = (void*)(ws + off);
    off += (bytes + 255) & ~(size_t)255;
    return p;
  };
  double* stats = (double*)alloc(256 * sizeof(double));
  float* t_sc  = (float*)alloc((size_t)N * 128 * 4);
  float* t_fc  = (float*)alloc((size_t)N * 128 * 4);
  float* agg   = (float*)alloc((size_t)N * 128 * 4);
  float* dis_s = (float*)alloc((size_t)N * 4);
  float* dis_f = (float*)alloc((size_t)N * 4);
  int*   rp_s  = (int*)alloc((size_t)(N + 1) * 4);
  int*   rp_f  = (int*)alloc((size_t)(N + 1) * 4);
  int*   cur_s = (int*)alloc((size_t)N * 4);
  int*   cur_f = (int*)alloc((size_t)N * 4);
  int*   src_s = (int*)alloc((size_t)E * 4);
  int*   src_f = (int*)alloc((size_t)E * 4);
  float* nw_s  = (float*)alloc((size_t)E * 4);
  float* nw_f  = (float*)alloc((size_t)E * 4);

  int nb_n = (N + THREADS - 1) / THREADS;           // 196
  int nb_e = (E + THREADS - 1) / THREADS;           // 2500

  // CSR + degree build (layer-invariant)
  k_init<<<nb_n, THREADS, 0, stream>>>(dis_s, dis_f, cur_s, cur_f, N);
  k_count<<<nb_e, THREADS, 0, stream>>>(ei_s + E, w_s, dis_s, cur_s, E);
  k_count<<<nb_e, THREADS, 0, stream>>>(ei_f + E, w_f, dis_f, cur_f, E);
  k_scan<<<2, THREADS, 0, stream>>>(cur_s, rp_s, cur_f, rp_f, N);
  k_dis<<<nb_n, THREADS, 0, stream>>>(dis_s, dis_f, N);
  k_scatter<<<nb_e, THREADS, 0, stream>>>(ei_s, w_s, dis_s, cur_s, src_s, nw_s, E);
  k_scatter<<<nb_e, THREADS, 0, stream>>>(ei_f, w_f, dis_f, cur_f, src_f, nw_f, E);

  const float* h = x;
  for (int l = 0; l < L; ++l) {
    dim3 gg((N + 31) / 32, 2);
    k_gemm<<<gg, THREADS, 0, stream>>>(h, W_s + (size_t)l * 128 * 128,
                                       W_f + (size_t)l * 128 * 128, t_sc, t_fc, N);
    k_gather<<<2048, THREADS, 0, stream>>>(t_sc, t_fc, rp_s, src_s, nw_s,
                                           rp_f, src_f, nw_f, dis_s, dis_f, agg, N);
    k_zero_stats<<<1, 256, 0, stream>>>(stats);
    k_stats<<<256, THREADS, 0, stream>>>(agg, stats, N);
    k_bn<<<2048, THREADS, 0, stream>>>(agg, stats, gamma + l * 128, beta + l * 128, out, N);
    h = out;   // layer-1 output lives in d_out; layer-2 overwrites it
  }
}

// Round 4
// 699.286 us; speedup vs baseline: 1.3018x; 1.3018x over previous
//
#include <hip/hip_runtime.h>
#include <hip/hip_bf16.h>

#define THREADS 256

// ---------- CSR build ----------
__global__ void k_init(float* deg_s, float* deg_f, int* cnt_s, int* cnt_f, int N) {
  for (int i = blockIdx.x * blockDim.x + threadIdx.x; i < N; i += gridDim.x * blockDim.x) {
    deg_s[i] = 1.0f; deg_f[i] = 1.0f;   // self-loop weight 1
    cnt_s[i] = 0;    cnt_f[i] = 0;
  }
}

__global__ void k_count(const int* __restrict__ col, const float* __restrict__ w,
                        float* deg, int* cnt, int E) {
  int e = blockIdx.x * blockDim.x + threadIdx.x;
  if (e < E) {
    int c = col[e];
    atomicAdd(&cnt[c], 1);
    atomicAdd(&deg[c], w[e]);
  }
}

// ---------- parallel exclusive scan (3 stages) ----------
// Stage 1: per-block inclusive scan of counts; write block-local exclusive
// into rp, per-block total into bsum[graph*nb + b].
__global__ void k_scan1(const int* __restrict__ cnt_s, const int* __restrict__ cnt_f,
                        int* __restrict__ rp_s, int* __restrict__ rp_f,
                        int* __restrict__ bsum, int N, int nb) {
  const int* cnt = blockIdx.y ? cnt_f : cnt_s;
  int*       rp  = blockIdx.y ? rp_f  : rp_s;
  __shared__ int buf[THREADS];
  int i = blockIdx.x * THREADS + threadIdx.x;
  int v = (i < N) ? cnt[i] : 0;
  buf[threadIdx.x] = v;
  __syncthreads();
  #pragma unroll
  for (int off = 1; off < THREADS; off <<= 1) {
    int t = (threadIdx.x >= off) ? buf[threadIdx.x - off] : 0;
    __syncthreads();
    buf[threadIdx.x] += t;
    __syncthreads();
  }
  if (i < N) rp[i] = buf[threadIdx.x] - v;          // block-local exclusive
  if (threadIdx.x == THREADS - 1) bsum[blockIdx.y * nb + blockIdx.x] = buf[THREADS - 1];
}

// Stage 2: exclusive-scan the block sums in place (nb <= 256; one block per graph).
__global__ void k_scan2(int* __restrict__ bsum, int nb) {
  __shared__ int buf[THREADS];
  int* b = bsum + blockIdx.x * nb;
  int v = (threadIdx.x < nb) ? b[threadIdx.x] : 0;
  buf[threadIdx.x] = v;
  __syncthreads();
  #pragma unroll
  for (int off = 1; off < THREADS; off <<= 1) {
    int t = (threadIdx.x >= off) ? buf[threadIdx.x - off] : 0;
    __syncthreads();
    buf[threadIdx.x] += t;
    __syncthreads();
  }
  if (threadIdx.x < nb) b[threadIdx.x] = buf[threadIdx.x] - v;   // exclusive
}

// Stage 3: add block offsets, init scatter cursor, set rp[N] = E.
__global__ void k_scan3(int* __restrict__ rp_s, int* __restrict__ rp_f,
                        int* __restrict__ cur_s, int* __restrict__ cur_f,
                        const int* __restrict__ bsum, int N, int nb, int E) {
  int* rp  = blockIdx.y ? rp_f  : rp_s;
  int* cur = blockIdx.y ? cur_f : cur_s;
  const int* bs = bsum + blockIdx.y * nb;
  int i = blockIdx.x * THREADS + threadIdx.x;
  if (i < N) {
    int e = rp[i] + bs[blockIdx.x];
    rp[i]  = e;
    cur[i] = e;
  }
  if (i == 0) rp[N] = E;
}

__global__ void k_dis(float* deg_s, float* deg_f, int N) {  // deg -> rsqrt(deg), in place
  for (int i = blockIdx.x * blockDim.x + threadIdx.x; i < N; i += gridDim.x * blockDim.x) {
    deg_s[i] = rsqrtf(deg_s[i]);
    deg_f[i] = rsqrtf(deg_f[i]);
  }
}

__global__ void k_scatter(const int* __restrict__ ei, const float* __restrict__ w,
                          const float* __restrict__ dis, int* cur,
                          int* __restrict__ src, float* __restrict__ nw, int E) {
  int e = blockIdx.x * blockDim.x + threadIdx.x;
  if (e < E) {
    int r = ei[e];
    int c = ei[E + e];
    int pos = atomicAdd(&cur[c], 1);
    src[pos] = r;
    nw[pos]  = dis[r] * w[e] * dis[c];
  }
}

// ---------- GEMM: C = A(N x 128) @ B(128 x 128), both branches via blockIdx.y ----------
__global__ __launch_bounds__(THREADS) void k_gemm(const float* __restrict__ A,
                                                  const float* __restrict__ B0,
                                                  const float* __restrict__ B1,
                                                  float* __restrict__ C0,
                                                  float* __restrict__ C1, int N) {
  const float* B = blockIdx.y ? B1 : B0;
  float*       C = blockIdx.y ? C1 : C0;
  __shared__ float Bs[128 * 128];   // 64 KiB
  int tid = threadIdx.x;
  #pragma unroll
  for (int i = 0; i < 16; ++i) {
    int idx = (i * THREADS + tid) * 4;
    *(float4*)&Bs[idx] = *(const float4*)&B[idx];
  }
  __syncthreads();

  int tr = tid >> 5;   // 0..7  -> 4 rows each
  int tc = tid & 31;   // 0..31 -> 4 cols each
  int r0 = blockIdx.x * 32;
  if (r0 >= N) return;
  int rbase = r0 + tr * 4;

  const float* ap[4];
  #pragma unroll
  for (int i = 0; i < 4; ++i) {
    int r = rbase + i; if (r > N - 1) r = N - 1;   // clamp; store is guarded
    ap[i] = A + (size_t)r * 128;
  }

  float acc[4][4] = {};
  for (int k4 = 0; k4 < 128; k4 += 4) {
    float4 a[4], b[4];
    #pragma unroll
    for (int i = 0; i < 4; ++i) a[i] = *(const float4*)(ap[i] + k4);
    #pragma unroll
    for (int kk = 0; kk < 4; ++kk) b[kk] = *(const float4*)&Bs[(k4 + kk) * 128 + tc * 4];
    #pragma unroll
    for (int i = 0; i < 4; ++i) {
      const float* av = (const float*)&a[i];
      #pragma unroll
      for (int kk = 0; kk < 4; ++kk) {
        acc[i][0] = fmaf(av[kk], b[kk].x, acc[i][0]);
        acc[i][1] = fmaf(av[kk], b[kk].y, acc[i][1]);
        acc[i][2] = fmaf(av[kk], b[kk].z, acc[i][2]);
        acc[i][3] = fmaf(av[kk], b[kk].w, acc[i][3]);
      }
    }
  }
  #pragma unroll
  for (int i = 0; i < 4; ++i) {
    int r = rbase + i;
    if (r < N)
      *(float4*)&C[(size_t)r * 128 + tc * 4] =
          make_float4(acc[i][0], acc[i][1], acc[i][2], acc[i][3]);
  }
}

// ---------- aggregation: agg[v] = t_sc[v]/deg_s + t_fc[v]/deg_f + sum_in-edges ----------
__global__ __launch_bounds__(THREADS) void k_gather(
    const float* __restrict__ t_sc, const float* __restrict__ t_fc,
    const int* __restrict__ rp_s, const int* __restrict__ src_s, const float* __restrict__ nw_s,
    const int* __restrict__ rp_f, const int* __restrict__ src_f, const float* __restrict__ nw_f,
    const float* __restrict__ dis_s, const float* __restrict__ dis_f,
    float* __restrict__ agg, int N) {
  int gw     = (blockIdx.x * blockDim.x + threadIdx.x) >> 6;
  int lane   = threadIdx.x & 63;
  int nwaves = (gridDim.x * blockDim.x) >> 6;
  for (int v = gw; v < N; v += nwaves) {
    float ds = dis_s[v], df = dis_f[v];
    float inv_s = ds * ds, inv_f = df * df;   // self-loop norm = 1/deg
    float2 a = ((const float2*)(t_sc + (size_t)v * 128))[lane];
    float2 b = ((const float2*)(t_fc + (size_t)v * 128))[lane];
    float ax = a.x * inv_s + b.x * inv_f;
    float ay = a.y * inv_s + b.y * inv_f;
    int e0 = rp_s[v], e1 = rp_s[v + 1];
    for (int e = e0; e < e1; ++e) {
      int s = src_s[e]; float w = nw_s[e];
      float2 tv = ((const float2*)(t_sc + (size_t)s * 128))[lane];
      ax = fmaf(tv.x, w, ax); ay = fmaf(tv.y, w, ay);
    }
    e0 = rp_f[v]; e1 = rp_f[v + 1];
    for (int e = e0; e < e1; ++e) {
      int s = src_f[e]; float w = nw_f[e];
      float2 tv = ((const float2*)(t_fc + (size_t)s * 128))[lane];
      ax = fmaf(tv.x, w, ax); ay = fmaf(tv.y, w, ay);
    }
    ((float2*)(agg + (size_t)v * 128))[lane] = make_float2(ax, ay);
  }
}

// ---------- BN stats + apply ----------
__global__ void k_zero_stats(double* stats) { stats[threadIdx.x] = 0.0; }

__global__ void k_stats(const float* __restrict__ agg, double* stats, int N) {
  __shared__ double sb[THREADS], qb[THREADS];
  int col  = threadIdx.x & 127;
  int half = threadIdx.x >> 7;
  double s = 0, q = 0;
  for (int r = blockIdx.x * 2 + half; r < N; r += gridDim.x * 2) {
    float v = agg[(size_t)r * 128 + col];
    s += v; q += (double)v * v;
  }
  sb[threadIdx.x] = s; qb[threadIdx.x] = q;
  __syncthreads();
  if (half == 0) {
    atomicAdd(&stats[col],       sb[threadIdx.x] + sb[threadIdx.x + 128]);
    atomicAdd(&stats[128 + col], qb[threadIdx.x] + qb[threadIdx.x + 128]);
  }
}

__global__ void k_bn(const float* __restrict__ agg, const double* __restrict__ stats,
                     const float* __restrict__ gamma, const float* __restrict__ beta,
                     float* __restrict__ out, int N) {
  int total = N * 128;
  double invN = 1.0 / (double)N;
  for (int i = blockIdx.x * blockDim.x + threadIdx.x; i < total; i += gridDim.x * blockDim.x) {
    int c = i & 127;
    double m   = stats[c] * invN;
    double var = stats[128 + c] * invN - m * m;
    float scale = gamma[c] * rsqrtf((float)var + 1e-5f);
    float shift = beta[c] - (float)m * scale;
    float v = fmaf(agg[i], scale, shift);
    out[i] = v > 0.f ? v : 0.f;
  }
}

extern "C" void kernel_launch(void* const* d_in, const int* in_sizes, int n_in,
                              void* d_out, int out_size, void* d_ws, size_t ws_size,
                              hipStream_t stream) {
  const float* x     = (const float*)d_in[0];
  const int*   ei_s  = (const int*)d_in[1];
  const float* w_s   = (const float*)d_in[2];
  const int*   ei_f  = (const int*)d_in[3];
  const float* w_f   = (const float*)d_in[4];
  const float* W_s   = (const float*)d_in[5];
  const float* W_f   = (const float*)d_in[7];
  const float* gamma = (const float*)d_in[9];
  const float* beta  = (const float*)d_in[10];
  float* out = (float*)d_out;

  const int N = in_sizes[0] / 128;
  const int E = in_sizes[2];
  const int L = in_sizes[5] / (128 * 128);

  char* ws = (char*)d_ws;
  size_t off = 0;
  auto alloc = [&](size_t bytes) -> void* {
    void* p = (void*)(ws + off);
    off += (bytes + 255) & ~(size_t)255;
    return p;
  };
  double* stats = (double*)alloc(256 * sizeof(double));
  float* t_sc  = (float*)alloc((size_t)N * 128 * 4);
  float* t_fc  = (float*)alloc((size_t)N * 128 * 4);
  float* agg   = (float*)alloc((size_t)N * 128 * 4);
  float* dis_s = (float*)alloc((size_t)N * 4);
  float* dis_f = (float*)alloc((size_t)N * 4);
  int*   rp_s  = (int*)alloc((size_t)(N + 1) * 4);
  int*   rp_f  = (int*)alloc((size_t)(N + 1) * 4);
  int*   cur_s = (int*)alloc((size_t)N * 4);
  int*   cur_f = (int*)alloc((size_t)N * 4);
  int*   src_s = (int*)alloc((size_t)E * 4);
  int*   src_f = (int*)alloc((size_t)E * 4);
  float* nw_s  = (float*)alloc((size_t)E * 4);
  float* nw_f  = (float*)alloc((size_t)E * 4);

  int nb_n = (N + THREADS - 1) / THREADS;           // 196
  int nb_e = (E + THREADS - 1) / THREADS;           // 2500
  int* bsum = (int*)alloc((size_t)2 * nb_n * 4);

  // CSR + degree build (layer-invariant)
  k_init<<<nb_n, THREADS, 0, stream>>>(dis_s, dis_f, cur_s, cur_f, N);
  k_count<<<nb_e, THREADS, 0, stream>>>(ei_s + E, w_s, dis_s, cur_s, E);
  k_count<<<nb_e, THREADS, 0, stream>>>(ei_f + E, w_f, dis_f, cur_f, E);
  {
    dim3 g1(nb_n, 2);
    k_scan1<<<g1, THREADS, 0, stream>>>(cur_s, cur_f, rp_s, rp_f, bsum, N, nb_n);
    k_scan2<<<2, THREADS, 0, stream>>>(bsum, nb_n);
    k_scan3<<<g1, THREADS, 0, stream>>>(rp_s, rp_f, cur_s, cur_f, bsum, N, nb_n, E);
  }
  k_dis<<<nb_n, THREADS, 0, stream>>>(dis_s, dis_f, N);
  k_scatter<<<nb_e, THREADS, 0, stream>>>(ei_s, w_s, dis_s, cur_s, src_s, nw_s, E);
  k_scatter<<<nb_e, THREADS, 0, stream>>>(ei_f, w_f, dis_f, cur_f, src_f, nw_f, E);

  const float* h = x;
  for (int l = 0; l < L; ++l) {
    dim3 gg((N + 31) / 32, 2);
    k_gemm<<<gg, THREADS, 0, stream>>>(h, W_s + (size_t)l * 128 * 128,
                                       W_f + (size_t)l * 128 * 128, t_sc, t_fc, N);
    k_gather<<<2048, THREADS, 0, stream>>>(t_sc, t_fc, rp_s, src_s, nw_s,
                                           rp_f, src_f, nw_f, dis_s, dis_f, agg, N);
    k_zero_stats<<<1, 256, 0, stream>>>(stats);
    k_stats<<<256, THREADS, 0, stream>>>(agg, stats, N);
    k_bn<<<2048, THREADS, 0, stream>>>(agg, stats, gamma + l * 128, beta + l * 128, out, N);
    h = out;   // layer-1 output lives in d_out; layer-2 overwrites it
  }
}

// Round 5
// 592.355 us; speedup vs baseline: 1.5368x; 1.1805x over previous
//
#include <hip/hip_runtime.h>
#include <hip/hip_bf16.h>

#define THREADS 256

// bf16 helpers (RNE)
static __device__ __forceinline__ unsigned short f2bf(float f) {
  union { float f; unsigned u; } v; v.f = f;
  unsigned r = (v.u + 0x7FFF + ((v.u >> 16) & 1)) >> 16;
  return (unsigned short)r;
}
static __device__ __forceinline__ float bf2f(unsigned short h) {
  union { unsigned u; float f; } v; v.u = ((unsigned)h) << 16;
  return v.f;
}

// ---------- CSR build ----------
__global__ void k_init(float* deg_s, float* deg_f, int* cnt_s, int* cnt_f, int N) {
  for (int i = blockIdx.x * blockDim.x + threadIdx.x; i < N; i += gridDim.x * blockDim.x) {
    deg_s[i] = 1.0f; deg_f[i] = 1.0f;   // self-loop weight 1
    cnt_s[i] = 0;    cnt_f[i] = 0;
  }
}

__global__ void k_count(const int* __restrict__ col, const float* __restrict__ w,
                        float* deg, int* cnt, int E) {
  int e = blockIdx.x * blockDim.x + threadIdx.x;
  if (e < E) {
    int c = col[e];
    atomicAdd(&cnt[c], 1);
    atomicAdd(&deg[c], w[e]);
  }
}

// ---------- parallel exclusive scan (3 stages) ----------
__global__ void k_scan1(const int* __restrict__ cnt_s, const int* __restrict__ cnt_f,
                        int* __restrict__ rp_s, int* __restrict__ rp_f,
                        int* __restrict__ bsum, int N, int nb) {
  const int* cnt = blockIdx.y ? cnt_f : cnt_s;
  int*       rp  = blockIdx.y ? rp_f  : rp_s;
  __shared__ int buf[THREADS];
  int i = blockIdx.x * THREADS + threadIdx.x;
  int v = (i < N) ? cnt[i] : 0;
  buf[threadIdx.x] = v;
  __syncthreads();
  #pragma unroll
  for (int off = 1; off < THREADS; off <<= 1) {
    int t = (threadIdx.x >= off) ? buf[threadIdx.x - off] : 0;
    __syncthreads();
    buf[threadIdx.x] += t;
    __syncthreads();
  }
  if (i < N) rp[i] = buf[threadIdx.x] - v;          // block-local exclusive
  if (threadIdx.x == THREADS - 1) bsum[blockIdx.y * nb + blockIdx.x] = buf[THREADS - 1];
}

__global__ void k_scan2(int* __restrict__ bsum, int nb) {
  __shared__ int buf[THREADS];
  int* b = bsum + blockIdx.x * nb;
  int v = (threadIdx.x < nb) ? b[threadIdx.x] : 0;
  buf[threadIdx.x] = v;
  __syncthreads();
  #pragma unroll
  for (int off = 1; off < THREADS; off <<= 1) {
    int t = (threadIdx.x >= off) ? buf[threadIdx.x - off] : 0;
    __syncthreads();
    buf[threadIdx.x] += t;
    __syncthreads();
  }
  if (threadIdx.x < nb) b[threadIdx.x] = buf[threadIdx.x] - v;   // exclusive
}

__global__ void k_scan3(int* __restrict__ rp_s, int* __restrict__ rp_f,
                        int* __restrict__ cur_s, int* __restrict__ cur_f,
                        const int* __restrict__ bsum, int N, int nb, int E) {
  int* rp  = blockIdx.y ? rp_f  : rp_s;
  int* cur = blockIdx.y ? cur_f : cur_s;
  const int* bs = bsum + blockIdx.y * nb;
  int i = blockIdx.x * THREADS + threadIdx.x;
  if (i < N) {
    int e = rp[i] + bs[blockIdx.x];
    rp[i]  = e;
    cur[i] = e;
  }
  if (i == 0) rp[N] = E;
}

__global__ void k_dis(float* deg_s, float* deg_f, int N) {  // deg -> rsqrt(deg), in place
  for (int i = blockIdx.x * blockDim.x + threadIdx.x; i < N; i += gridDim.x * blockDim.x) {
    deg_s[i] = rsqrtf(deg_s[i]);
    deg_f[i] = rsqrtf(deg_f[i]);
  }
}

__global__ void k_scatter(const int* __restrict__ ei, const float* __restrict__ w,
                          const float* __restrict__ dis, int* cur,
                          int* __restrict__ src, float* __restrict__ nw, int E) {
  int e = blockIdx.x * blockDim.x + threadIdx.x;
  if (e < E) {
    int r = ei[e];
    int c = ei[E + e];
    int pos = atomicAdd(&cur[c], 1);
    src[pos] = r;
    nw[pos]  = dis[r] * w[e] * dis[c];
  }
}

// ---------- GEMM: C(bf16) = A(N x 128, f32) @ B(128 x 128, f32) ----------
__global__ __launch_bounds__(THREADS) void k_gemm(const float* __restrict__ A,
                                                  const float* __restrict__ B0,
                                                  const float* __restrict__ B1,
                                                  unsigned short* __restrict__ C0,
                                                  unsigned short* __restrict__ C1, int N) {
  const float*    B = blockIdx.y ? B1 : B0;
  unsigned short* C = blockIdx.y ? C1 : C0;
  __shared__ float Bs[128 * 128];   // 64 KiB
  int tid = threadIdx.x;
  #pragma unroll
  for (int i = 0; i < 16; ++i) {
    int idx = (i * THREADS + tid) * 4;
    *(float4*)&Bs[idx] = *(const float4*)&B[idx];
  }
  __syncthreads();

  int tr = tid >> 5;   // 0..7  -> 4 rows each
  int tc = tid & 31;   // 0..31 -> 4 cols each
  int r0 = blockIdx.x * 32;
  if (r0 >= N) return;
  int rbase = r0 + tr * 4;

  const float* ap[4];
  #pragma unroll
  for (int i = 0; i < 4; ++i) {
    int r = rbase + i; if (r > N - 1) r = N - 1;   // clamp; store is guarded
    ap[i] = A + (size_t)r * 128;
  }

  float acc[4][4] = {};
  for (int k4 = 0; k4 < 128; k4 += 4) {
    float4 a[4], b[4];
    #pragma unroll
    for (int i = 0; i < 4; ++i) a[i] = *(const float4*)(ap[i] + k4);
    #pragma unroll
    for (int kk = 0; kk < 4; ++kk) b[kk] = *(const float4*)&Bs[(k4 + kk) * 128 + tc * 4];
    #pragma unroll
    for (int i = 0; i < 4; ++i) {
      const float* av = (const float*)&a[i];
      #pragma unroll
      for (int kk = 0; kk < 4; ++kk) {
        acc[i][0] = fmaf(av[kk], b[kk].x, acc[i][0]);
        acc[i][1] = fmaf(av[kk], b[kk].y, acc[i][1]);
        acc[i][2] = fmaf(av[kk], b[kk].z, acc[i][2]);
        acc[i][3] = fmaf(av[kk], b[kk].w, acc[i][3]);
      }
    }
  }
  #pragma unroll
  for (int i = 0; i < 4; ++i) {
    int r = rbase + i;
    if (r < N) {
      ushort4 o;
      o.x = f2bf(acc[i][0]); o.y = f2bf(acc[i][1]);
      o.z = f2bf(acc[i][2]); o.w = f2bf(acc[i][3]);
      *(ushort4*)&C[(size_t)r * 128 + tc * 4] = o;
    }
  }
}

// ---------- aggregation over bf16 t-buffers ----------
// agg[v] = t_sc[v]/deg_s + t_fc[v]/deg_f + sum over in-edges (both graphs).
// One wave per vertex; lane handles cols {2*lane, 2*lane+1} (ushort2 = 4B).
__global__ __launch_bounds__(THREADS) void k_gather(
    const unsigned short* __restrict__ t_sc, const unsigned short* __restrict__ t_fc,
    const int* __restrict__ rp_s, const int* __restrict__ src_s, const float* __restrict__ nw_s,
    const int* __restrict__ rp_f, const int* __restrict__ src_f, const float* __restrict__ nw_f,
    const float* __restrict__ dis_s, const float* __restrict__ dis_f,
    float* __restrict__ agg, int N) {
  int gw     = (blockIdx.x * blockDim.x + threadIdx.x) >> 6;
  int lane   = threadIdx.x & 63;
  int nwaves = (gridDim.x * blockDim.x) >> 6;
  for (int v = gw; v < N; v += nwaves) {
    float ds = dis_s[v], df = dis_f[v];
    float inv_s = ds * ds, inv_f = df * df;   // self-loop norm = 1/deg
    unsigned a = ((const unsigned*)(t_sc + (size_t)v * 128))[lane];
    unsigned b = ((const unsigned*)(t_fc + (size_t)v * 128))[lane];
    float ax = bf2f((unsigned short)a) * inv_s + bf2f((unsigned short)b) * inv_f;
    float ay = bf2f((unsigned short)(a >> 16)) * inv_s + bf2f((unsigned short)(b >> 16)) * inv_f;

    int e0 = rp_s[v], e1 = rp_s[v + 1];
    int e = e0;
    for (; e + 1 < e1; e += 2) {          // 2 independent row loads in flight
      int s0 = src_s[e],  s1 = src_s[e + 1];
      float w0 = nw_s[e], w1 = nw_s[e + 1];
      unsigned r0 = ((const unsigned*)(t_sc + (size_t)s0 * 128))[lane];
      unsigned r1 = ((const unsigned*)(t_sc + (size_t)s1 * 128))[lane];
      ax = fmaf(bf2f((unsigned short)r0), w0, ax);
      ay = fmaf(bf2f((unsigned short)(r0 >> 16)), w0, ay);
      ax = fmaf(bf2f((unsigned short)r1), w1, ax);
      ay = fmaf(bf2f((unsigned short)(r1 >> 16)), w1, ay);
    }
    if (e < e1) {
      int s0 = src_s[e]; float w0 = nw_s[e];
      unsigned r0 = ((const unsigned*)(t_sc + (size_t)s0 * 128))[lane];
      ax = fmaf(bf2f((unsigned short)r0), w0, ax);
      ay = fmaf(bf2f((unsigned short)(r0 >> 16)), w0, ay);
    }

    e0 = rp_f[v]; e1 = rp_f[v + 1];
    e = e0;
    for (; e + 1 < e1; e += 2) {
      int s0 = src_f[e],  s1 = src_f[e + 1];
      float w0 = nw_f[e], w1 = nw_f[e + 1];
      unsigned r0 = ((const unsigned*)(t_fc + (size_t)s0 * 128))[lane];
      unsigned r1 = ((const unsigned*)(t_fc + (size_t)s1 * 128))[lane];
      ax = fmaf(bf2f((unsigned short)r0), w0, ax);
      ay = fmaf(bf2f((unsigned short)(r0 >> 16)), w0, ay);
      ax = fmaf(bf2f((unsigned short)r1), w1, ax);
      ay = fmaf(bf2f((unsigned short)(r1 >> 16)), w1, ay);
    }
    if (e < e1) {
      int s0 = src_f[e]; float w0 = nw_f[e];
      unsigned r0 = ((const unsigned*)(t_fc + (size_t)s0 * 128))[lane];
      ax = fmaf(bf2f((unsigned short)r0), w0, ax);
      ay = fmaf(bf2f((unsigned short)(r0 >> 16)), w0, ay);
    }
    ((float2*)(agg + (size_t)v * 128))[lane] = make_float2(ax, ay);
  }
}

// ---------- BN stats + apply ----------
__global__ void k_zero_stats(double* stats) { stats[threadIdx.x] = 0.0; }

__global__ void k_stats(const float* __restrict__ agg, double* stats, int N) {
  __shared__ double sb[THREADS], qb[THREADS];
  int col  = threadIdx.x & 127;
  int half = threadIdx.x >> 7;
  double s = 0, q = 0;
  for (int r = blockIdx.x * 2 + half; r < N; r += gridDim.x * 2) {
    float v = agg[(size_t)r * 128 + col];
    s += v; q += (double)v * v;
  }
  sb[threadIdx.x] = s; qb[threadIdx.x] = q;
  __syncthreads();
  if (half == 0) {
    atomicAdd(&stats[col],       sb[threadIdx.x] + sb[threadIdx.x + 128]);
    atomicAdd(&stats[128 + col], qb[threadIdx.x] + qb[threadIdx.x + 128]);
  }
}

__global__ void k_bn(const float* __restrict__ agg, const double* __restrict__ stats,
                     const float* __restrict__ gamma, const float* __restrict__ beta,
                     float* __restrict__ out, int N) {
  int total = N * 128;
  double invN = 1.0 / (double)N;
  for (int i = blockIdx.x * blockDim.x + threadIdx.x; i < total; i += gridDim.x * blockDim.x) {
    int c = i & 127;
    double m   = stats[c] * invN;
    double var = stats[128 + c] * invN - m * m;
    float scale = gamma[c] * rsqrtf((float)var + 1e-5f);
    float shift = beta[c] - (float)m * scale;
    float v = fmaf(agg[i], scale, shift);
    out[i] = v > 0.f ? v : 0.f;
  }
}

extern "C" void kernel_launch(void* const* d_in, const int* in_sizes, int n_in,
                              void* d_out, int out_size, void* d_ws, size_t ws_size,
                              hipStream_t stream) {
  const float* x     = (const float*)d_in[0];
  const int*   ei_s  = (const int*)d_in[1];
  const float* w_s   = (const float*)d_in[2];
  const int*   ei_f  = (const int*)d_in[3];
  const float* w_f   = (const float*)d_in[4];
  const float* W_s   = (const float*)d_in[5];
  const float* W_f   = (const float*)d_in[7];
  const float* gamma = (const float*)d_in[9];
  const float* beta  = (const float*)d_in[10];
  float* out = (float*)d_out;

  const int N = in_sizes[0] / 128;
  const int E = in_sizes[2];
  const int L = in_sizes[5] / (128 * 128);

  char* ws = (char*)d_ws;
  size_t off = 0;
  auto alloc = [&](size_t bytes) -> void* {
    void* p = (void*)(ws + off);
    off += (bytes + 255) & ~(size_t)255;
    return p;
  };
  double* stats = (double*)alloc(256 * sizeof(double));
  unsigned short* t_sc = (unsigned short*)alloc((size_t)N * 128 * 2);
  unsigned short* t_fc = (unsigned short*)alloc((size_t)N * 128 * 2);
  float* agg   = (float*)alloc((size_t)N * 128 * 4);
  float* dis_s = (float*)alloc((size_t)N * 4);
  float* dis_f = (float*)alloc((size_t)N * 4);
  int*   rp_s  = (int*)alloc((size_t)(N + 1) * 4);
  int*   rp_f  = (int*)alloc((size_t)(N + 1) * 4);
  int*   cur_s = (int*)alloc((size_t)N * 4);
  int*   cur_f = (int*)alloc((size_t)N * 4);
  int*   src_s = (int*)alloc((size_t)E * 4);
  int*   src_f = (int*)alloc((size_t)E * 4);
  float* nw_s  = (float*)alloc((size_t)E * 4);
  float* nw_f  = (float*)alloc((size_t)E * 4);

  int nb_n = (N + THREADS - 1) / THREADS;           // 196
  int nb_e = (E + THREADS - 1) / THREADS;           // 2500
  int* bsum = (int*)alloc((size_t)2 * nb_n * 4);

  // CSR + degree build (layer-invariant)
  k_init<<<nb_n, THREADS, 0, stream>>>(dis_s, dis_f, cur_s, cur_f, N);
  k_count<<<nb_e, THREADS, 0, stream>>>(ei_s + E, w_s, dis_s, cur_s, E);
  k_count<<<nb_e, THREADS, 0, stream>>>(ei_f + E, w_f, dis_f, cur_f, E);
  {
    dim3 g1(nb_n, 2);
    k_scan1<<<g1, THREADS, 0, stream>>>(cur_s, cur_f, rp_s, rp_f, bsum, N, nb_n);
    k_scan2<<<2, THREADS, 0, stream>>>(bsum, nb_n);
    k_scan3<<<g1, THREADS, 0, stream>>>(rp_s, rp_f, cur_s, cur_f, bsum, N, nb_n, E);
  }
  k_dis<<<nb_n, THREADS, 0, stream>>>(dis_s, dis_f, N);
  k_scatter<<<nb_e, THREADS, 0, stream>>>(ei_s, w_s, dis_s, cur_s, src_s, nw_s, E);
  k_scatter<<<nb_e, THREADS, 0, stream>>>(ei_f, w_f, dis_f, cur_f, src_f, nw_f, E);

  const float* h = x;
  for (int l = 0; l < L; ++l) {
    dim3 gg((N + 31) / 32, 2);
    k_gemm<<<gg, THREADS, 0, stream>>>(h, W_s + (size_t)l * 128 * 128,
                                       W_f + (size_t)l * 128 * 128, t_sc, t_fc, N);
    k_gather<<<2048, THREADS, 0, stream>>>(t_sc, t_fc, rp_s, src_s, nw_s,
                                           rp_f, src_f, nw_f, dis_s, dis_f, agg, N);
    k_zero_stats<<<1, 256, 0, stream>>>(stats);
    k_stats<<<256, THREADS, 0, stream>>>(agg, stats, N);
    k_bn<<<2048, THREADS, 0, stream>>>(agg, stats, gamma + l * 128, beta + l * 128, out, N);
    h = out;   // layer-1 output lives in d_out; layer-2 overwrites it
  }
}

// Round 6
// 568.960 us; speedup vs baseline: 1.5999x; 1.0411x over previous
//
#include <hip/hip_runtime.h>
#include <hip/hip_bf16.h>

#define THREADS 256

typedef __attribute__((ext_vector_type(8))) short s16x8;   // 8 bf16 = 4 VGPR
typedef __attribute__((ext_vector_type(4))) float f32x4;

// bf16 helpers (RNE)
static __device__ __forceinline__ unsigned short f2bf(float f) {
  union { float f; unsigned u; } v; v.f = f;
  unsigned r = (v.u + 0x7FFF + ((v.u >> 16) & 1)) >> 16;
  return (unsigned short)r;
}
static __device__ __forceinline__ float bf2f(unsigned short h) {
  union { unsigned u; float f; } v; v.u = ((unsigned)h) << 16;
  return v.f;
}

// ---------- CSR build ----------
__global__ void k_init(float* deg_s, float* deg_f, int* cnt_s, int* cnt_f, int N) {
  for (int i = blockIdx.x * blockDim.x + threadIdx.x; i < N; i += gridDim.x * blockDim.x) {
    deg_s[i] = 1.0f; deg_f[i] = 1.0f;   // self-loop weight 1
    cnt_s[i] = 0;    cnt_f[i] = 0;
  }
}

__global__ void k_count(const int* __restrict__ col, const float* __restrict__ w,
                        float* deg, int* cnt, int E) {
  int e = blockIdx.x * blockDim.x + threadIdx.x;
  if (e < E) {
    int c = col[e];
    atomicAdd(&cnt[c], 1);
    atomicAdd(&deg[c], w[e]);
  }
}

// ---------- parallel exclusive scan (3 stages) ----------
__global__ void k_scan1(const int* __restrict__ cnt_s, const int* __restrict__ cnt_f,
                        int* __restrict__ rp_s, int* __restrict__ rp_f,
                        int* __restrict__ bsum, int N, int nb) {
  const int* cnt = blockIdx.y ? cnt_f : cnt_s;
  int*       rp  = blockIdx.y ? rp_f  : rp_s;
  __shared__ int buf[THREADS];
  int i = blockIdx.x * THREADS + threadIdx.x;
  int v = (i < N) ? cnt[i] : 0;
  buf[threadIdx.x] = v;
  __syncthreads();
  #pragma unroll
  for (int off = 1; off < THREADS; off <<= 1) {
    int t = (threadIdx.x >= off) ? buf[threadIdx.x - off] : 0;
    __syncthreads();
    buf[threadIdx.x] += t;
    __syncthreads();
  }
  if (i < N) rp[i] = buf[threadIdx.x] - v;          // block-local exclusive
  if (threadIdx.x == THREADS - 1) bsum[blockIdx.y * nb + blockIdx.x] = buf[THREADS - 1];
}

__global__ void k_scan2(int* __restrict__ bsum, int nb) {
  __shared__ int buf[THREADS];
  int* b = bsum + blockIdx.x * nb;
  int v = (threadIdx.x < nb) ? b[threadIdx.x] : 0;
  buf[threadIdx.x] = v;
  __syncthreads();
  #pragma unroll
  for (int off = 1; off < THREADS; off <<= 1) {
    int t = (threadIdx.x >= off) ? buf[threadIdx.x - off] : 0;
    __syncthreads();
    buf[threadIdx.x] += t;
    __syncthreads();
  }
  if (threadIdx.x < nb) b[threadIdx.x] = buf[threadIdx.x] - v;   // exclusive
}

__global__ void k_scan3(int* __restrict__ rp_s, int* __restrict__ rp_f,
                        int* __restrict__ cur_s, int* __restrict__ cur_f,
                        const int* __restrict__ bsum, int N, int nb, int E) {
  int* rp  = blockIdx.y ? rp_f  : rp_s;
  int* cur = blockIdx.y ? cur_f : cur_s;
  const int* bs = bsum + blockIdx.y * nb;
  int i = blockIdx.x * THREADS + threadIdx.x;
  if (i < N) {
    int e = rp[i] + bs[blockIdx.x];
    rp[i]  = e;
    cur[i] = e;
  }
  if (i == 0) rp[N] = E;
}

__global__ void k_dis(float* deg_s, float* deg_f, int N) {  // deg -> rsqrt(deg), in place
  for (int i = blockIdx.x * blockDim.x + threadIdx.x; i < N; i += gridDim.x * blockDim.x) {
    deg_s[i] = rsqrtf(deg_s[i]);
    deg_f[i] = rsqrtf(deg_f[i]);
  }
}

__global__ void k_scatter(const int* __restrict__ ei, const float* __restrict__ w,
                          const float* __restrict__ dis, int* cur,
                          int* __restrict__ src, float* __restrict__ nw, int E) {
  int e = blockIdx.x * blockDim.x + threadIdx.x;
  if (e < E) {
    int r = ei[e];
    int c = ei[E + e];
    int pos = atomicAdd(&cur[c], 1);
    src[pos] = r;
    nw[pos]  = dis[r] * w[e] * dis[c];
  }
}

// ---------- cast x (f32) -> bf16 ----------
__global__ void k_cast(const float* __restrict__ in, unsigned short* __restrict__ out, int total4) {
  for (int i = blockIdx.x * blockDim.x + threadIdx.x; i < total4; i += gridDim.x * blockDim.x) {
    float4 v = ((const float4*)in)[i];
    ushort4 o;
    o.x = f2bf(v.x); o.y = f2bf(v.y); o.z = f2bf(v.z); o.w = f2bf(v.w);
    ((ushort4*)out)[i] = o;
  }
}

// ---------- MFMA GEMM: C(bf16) = A(N x 128, bf16) @ W(128 x 128, f32) ----------
// Block: 256 thr = 4 waves, 64 rows. W staged transposed (Wt[n][k]) bf16 in LDS,
// XOR-swizzled (byte ^= (n&7)<<4) so the 16-lane col-slice ds_read_b128 is 2-way (free).
__global__ __launch_bounds__(THREADS) void k_gemm_mfma(
    const unsigned short* __restrict__ A,
    const float* __restrict__ B0, const float* __restrict__ B1,
    unsigned short* __restrict__ C0, unsigned short* __restrict__ C1, int N) {
  const float*    W = blockIdx.y ? B1 : B0;
  unsigned short* C = blockIdx.y ? C1 : C0;
  __shared__ unsigned short Wt[128 * 128];   // 32 KiB, [n][k] swizzled
  int tid = threadIdx.x;
  #pragma unroll
  for (int p = 0; p < 32; ++p) {             // 128 n * 64 kpairs / 256 thr
    int idx = p * 256 + tid;
    int kp = idx & 63, n = idx >> 6;         // k = 2*kp
    float w0 = W[(2 * kp) * 128 + n];
    float w1 = W[(2 * kp + 1) * 128 + n];
    unsigned pk = (unsigned)f2bf(w0) | ((unsigned)f2bf(w1) << 16);
    unsigned byte = (unsigned)(n * 256 + kp * 4) ^ ((unsigned)(n & 7) << 4);
    *(unsigned*)((char*)Wt + byte) = pk;
  }
  __syncthreads();

  int wid = tid >> 6, lane = tid & 63;
  int row0 = blockIdx.x * 64 + wid * 16;
  int rowA = row0 + (lane & 15); if (rowA > N - 1) rowA = N - 1;   // clamp; store guarded
  const unsigned short* arow = A + (size_t)rowA * 128;
  int kg = lane >> 4;                        // 0..3

  f32x4 acc[8];
  #pragma unroll
  for (int nt = 0; nt < 8; ++nt) acc[nt] = (f32x4){0.f, 0.f, 0.f, 0.f};

  #pragma unroll
  for (int ks = 0; ks < 4; ++ks) {
    s16x8 afrag = *(const s16x8*)(arow + ks * 32 + kg * 8);
    #pragma unroll
    for (int nt = 0; nt < 8; ++nt) {
      int col = nt * 16 + (lane & 15);
      unsigned byte = (unsigned)(col * 256 + (ks * 32 + kg * 8) * 2) ^ ((unsigned)(col & 7) << 4);
      s16x8 bfrag = *(const s16x8*)((char*)Wt + byte);
      acc[nt] = __builtin_amdgcn_mfma_f32_16x16x32_bf16(afrag, bfrag, acc[nt], 0, 0, 0);
    }
  }
  // C/D layout (m89): col = lane&15, row = (lane>>4)*4 + reg
  #pragma unroll
  for (int nt = 0; nt < 8; ++nt) {
    int col = nt * 16 + (lane & 15);
    #pragma unroll
    for (int r = 0; r < 4; ++r) {
      int row = row0 + kg * 4 + r;
      if (row < N) C[(size_t)row * 128 + col] = f2bf(acc[nt][r]);
    }
  }
}

// ---------- aggregation over bf16 t-buffers ----------
__global__ __launch_bounds__(THREADS) void k_gather(
    const unsigned short* __restrict__ t_sc, const unsigned short* __restrict__ t_fc,
    const int* __restrict__ rp_s, const int* __restrict__ src_s, const float* __restrict__ nw_s,
    const int* __restrict__ rp_f, const int* __restrict__ src_f, const float* __restrict__ nw_f,
    const float* __restrict__ dis_s, const float* __restrict__ dis_f,
    float* __restrict__ agg, int N) {
  int gw     = (blockIdx.x * blockDim.x + threadIdx.x) >> 6;
  int lane   = threadIdx.x & 63;
  int nwaves = (gridDim.x * blockDim.x) >> 6;
  for (int v = gw; v < N; v += nwaves) {
    float ds = dis_s[v], df = dis_f[v];
    float inv_s = ds * ds, inv_f = df * df;   // self-loop norm = 1/deg
    unsigned a = ((const unsigned*)(t_sc + (size_t)v * 128))[lane];
    unsigned b = ((const unsigned*)(t_fc + (size_t)v * 128))[lane];
    float ax = bf2f((unsigned short)a) * inv_s + bf2f((unsigned short)b) * inv_f;
    float ay = bf2f((unsigned short)(a >> 16)) * inv_s + bf2f((unsigned short)(b >> 16)) * inv_f;

    #pragma unroll 1
    for (int g = 0; g < 2; ++g) {
      const int*            rp  = g ? rp_f  : rp_s;
      const int*            src = g ? src_f : src_s;
      const float*          nw  = g ? nw_f  : nw_s;
      const unsigned short* t   = g ? t_fc  : t_sc;
      int e0 = rp[v], e1 = rp[v + 1];
      int e = e0;
      for (; e + 3 < e1; e += 4) {          // 4 independent row loads in flight
        int   s0 = src[e],     s1 = src[e + 1], s2 = src[e + 2], s3 = src[e + 3];
        float w0 = nw[e],      w1 = nw[e + 1],  w2 = nw[e + 2],  w3 = nw[e + 3];
        unsigned r0 = ((const unsigned*)(t + (size_t)s0 * 128))[lane];
        unsigned r1 = ((const unsigned*)(t + (size_t)s1 * 128))[lane];
        unsigned r2 = ((const unsigned*)(t + (size_t)s2 * 128))[lane];
        unsigned r3 = ((const unsigned*)(t + (size_t)s3 * 128))[lane];
        ax = fmaf(bf2f((unsigned short)r0), w0, ax); ay = fmaf(bf2f((unsigned short)(r0 >> 16)), w0, ay);
        ax = fmaf(bf2f((unsigned short)r1), w1, ax); ay = fmaf(bf2f((unsigned short)(r1 >> 16)), w1, ay);
        ax = fmaf(bf2f((unsigned short)r2), w2, ax); ay = fmaf(bf2f((unsigned short)(r2 >> 16)), w2, ay);
        ax = fmaf(bf2f((unsigned short)r3), w3, ax); ay = fmaf(bf2f((unsigned short)(r3 >> 16)), w3, ay);
      }
      for (; e < e1; ++e) {
        int s0 = src[e]; float w0 = nw[e];
        unsigned r0 = ((const unsigned*)(t + (size_t)s0 * 128))[lane];
        ax = fmaf(bf2f((unsigned short)r0), w0, ax);
        ay = fmaf(bf2f((unsigned short)(r0 >> 16)), w0, ay);
      }
    }
    ((float2*)(agg + (size_t)v * 128))[lane] = make_float2(ax, ay);
  }
}

// ---------- BN stats + apply ----------
__global__ void k_zero_stats(double* stats) { stats[threadIdx.x] = 0.0; }

__global__ void k_stats(const float* __restrict__ agg, double* stats, int N) {
  __shared__ double sb[THREADS], qb[THREADS];
  int col  = threadIdx.x & 127;
  int half = threadIdx.x >> 7;
  double s = 0, q = 0;
  for (int r = blockIdx.x * 2 + half; r < N; r += gridDim.x * 2) {
    float v = agg[(size_t)r * 128 + col];
    s += v; q += (double)v * v;
  }
  sb[threadIdx.x] = s; qb[threadIdx.x] = q;
  __syncthreads();
  if (half == 0) {
    atomicAdd(&stats[col],       sb[threadIdx.x] + sb[threadIdx.x + 128]);
    atomicAdd(&stats[128 + col], qb[threadIdx.x] + qb[threadIdx.x + 128]);
  }
}

// last==0: write bf16 h for next layer's GEMM. last==1: write f32 d_out.
__global__ void k_bn(const float* __restrict__ agg, const double* __restrict__ stats,
                     const float* __restrict__ gamma, const float* __restrict__ beta,
                     unsigned short* __restrict__ outb, float* __restrict__ outf,
                     int N, int last) {
  int total = N * 128;
  double invN = 1.0 / (double)N;
  for (int i = blockIdx.x * blockDim.x + threadIdx.x; i < total; i += gridDim.x * blockDim.x) {
    int c = i & 127;
    double m   = stats[c] * invN;
    double var = stats[128 + c] * invN - m * m;
    float scale = gamma[c] * rsqrtf((float)var + 1e-5f);
    float shift = beta[c] - (float)m * scale;
    float v = fmaf(agg[i], scale, shift);
    v = v > 0.f ? v : 0.f;
    if (last) outf[i] = v;
    else      outb[i] = f2bf(v);
  }
}

extern "C" void kernel_launch(void* const* d_in, const int* in_sizes, int n_in,
                              void* d_out, int out_size, void* d_ws, size_t ws_size,
                              hipStream_t stream) {
  const float* x     = (const float*)d_in[0];
  const int*   ei_s  = (const int*)d_in[1];
  const float* w_s   = (const float*)d_in[2];
  const int*   ei_f  = (const int*)d_in[3];
  const float* w_f   = (const float*)d_in[4];
  const float* W_s   = (const float*)d_in[5];
  const float* W_f   = (const float*)d_in[7];
  const float* gamma = (const float*)d_in[9];
  const float* beta  = (const float*)d_in[10];
  float* out = (float*)d_out;

  const int N = in_sizes[0] / 128;
  const int E = in_sizes[2];
  const int L = in_sizes[5] / (128 * 128);

  char* ws = (char*)d_ws;
  size_t off = 0;
  auto alloc = [&](size_t bytes) -> void* {
    void* p = (void*)(ws + off);
    off += (bytes + 255) & ~(size_t)255;
    return p;
  };
  double* stats = (double*)alloc(256 * sizeof(double));
  unsigned short* t_sc = (unsigned short*)alloc((size_t)N * 128 * 2);
  unsigned short* t_fc = (unsigned short*)alloc((size_t)N * 128 * 2);
  unsigned short* hb   = (unsigned short*)alloc((size_t)N * 128 * 2);
  float* agg   = (float*)alloc((size_t)N * 128 * 4);
  float* dis_s = (float*)alloc((size_t)N * 4);
  float* dis_f = (float*)alloc((size_t)N * 4);
  int*   rp_s  = (int*)alloc((size_t)(N + 1) * 4);
  int*   rp_f  = (int*)alloc((size_t)(N + 1) * 4);
  int*   cur_s = (int*)alloc((size_t)N * 4);
  int*   cur_f = (int*)alloc((size_t)N * 4);
  int*   src_s = (int*)alloc((size_t)E * 4);
  int*   src_f = (int*)alloc((size_t)E * 4);
  float* nw_s  = (float*)alloc((size_t)E * 4);
  float* nw_f  = (float*)alloc((size_t)E * 4);

  int nb_n = (N + THREADS - 1) / THREADS;           // 196
  int nb_e = (E + THREADS - 1) / THREADS;           // 2500
  int* bsum = (int*)alloc((size_t)2 * nb_n * 4);

  // CSR + degree build (layer-invariant)
  k_init<<<nb_n, THREADS, 0, stream>>>(dis_s, dis_f, cur_s, cur_f, N);
  k_count<<<nb_e, THREADS, 0, stream>>>(ei_s + E, w_s, dis_s, cur_s, E);
  k_count<<<nb_e, THREADS, 0, stream>>>(ei_f + E, w_f, dis_f, cur_f, E);
  {
    dim3 g1(nb_n, 2);
    k_scan1<<<g1, THREADS, 0, stream>>>(cur_s, cur_f, rp_s, rp_f, bsum, N, nb_n);
    k_scan2<<<2, THREADS, 0, stream>>>(bsum, nb_n);
    k_scan3<<<g1, THREADS, 0, stream>>>(rp_s, rp_f, cur_s, cur_f, bsum, N, nb_n, E);
  }
  k_dis<<<nb_n, THREADS, 0, stream>>>(dis_s, dis_f, N);
  k_scatter<<<nb_e, THREADS, 0, stream>>>(ei_s, w_s, dis_s, cur_s, src_s, nw_s, E);
  k_scatter<<<nb_e, THREADS, 0, stream>>>(ei_f, w_f, dis_f, cur_f, src_f, nw_f, E);

  k_cast<<<1024, THREADS, 0, stream>>>(x, hb, N * 128 / 4);

  for (int l = 0; l < L; ++l) {
    dim3 gg((N + 63) / 64, 2);
    k_gemm_mfma<<<gg, THREADS, 0, stream>>>(hb, W_s + (size_t)l * 128 * 128,
                                            W_f + (size_t)l * 128 * 128, t_sc, t_fc, N);
    k_gather<<<2048, THREADS, 0, stream>>>(t_sc, t_fc, rp_s, src_s, nw_s,
                                           rp_f, src_f, nw_f, dis_s, dis_f, agg, N);
    k_zero_stats<<<1, 256, 0, stream>>>(stats);
    k_stats<<<256, THREADS, 0, stream>>>(agg, stats, N);
    k_bn<<<2048, THREADS, 0, stream>>>(agg, stats, gamma + l * 128, beta + l * 128,
                                       hb, out, N, (l == L - 1) ? 1 : 0);
  }
}

// Round 8
// 481.113 us; speedup vs baseline: 1.8921x; 1.1826x over previous
//
#include <hip/hip_runtime.h>
#include <hip/hip_bf16.h>

#define THREADS 256
#define FIXS 67108864.0f   // 2^26 fixed-point scale for weight sums

typedef __attribute__((ext_vector_type(8))) short s16x8;   // 8 bf16 = 4 VGPR
typedef __attribute__((ext_vector_type(4))) float f32x4;

// bf16 helpers (RNE)
static __device__ __forceinline__ unsigned short f2bf(float f) {
  union { float f; unsigned u; } v; v.f = f;
  unsigned r = (v.u + 0x7FFF + ((v.u >> 16) & 1)) >> 16;
  return (unsigned short)r;
}
static __device__ __forceinline__ float bf2f(unsigned short h) {
  union { unsigned u; float f; } v; v.u = ((unsigned)h) << 16;
  return v.f;
}

// ---------- CSR build ----------
__global__ void k_init(unsigned long long* pk_s, unsigned long long* pk_f, int N) {
  for (int i = blockIdx.x * blockDim.x + threadIdx.x; i < N; i += gridDim.x * blockDim.x) {
    pk_s[i] = 0ULL; pk_f[i] = 0ULL;
  }
}

// one u64 atomic per edge: count in high 24 bits, Σw in 2^-26 fixed point low 40 bits
__global__ void k_count2(const int* __restrict__ col_s, const float* __restrict__ w_s,
                         const int* __restrict__ col_f, const float* __restrict__ w_f,
                         unsigned long long* pk_s, unsigned long long* pk_f, int E) {
  const int*          col = blockIdx.y ? col_f : col_s;
  const float*        w   = blockIdx.y ? w_f  : w_s;
  unsigned long long* pk  = blockIdx.y ? pk_f : pk_s;
  int e = blockIdx.x * blockDim.x + threadIdx.x;
  if (e < E) {
    unsigned long long fx = (unsigned long long)(w[e] * FIXS + 0.5f);
    atomicAdd(&pk[col[e]], (1ULL << 40) | fx);
  }
}

// unpack: cnt (for scan) + dis = rsqrt(1 + Σw)
__global__ void k_pre(const unsigned long long* __restrict__ pk_s,
                      const unsigned long long* __restrict__ pk_f,
                      int* __restrict__ cnt_s, int* __restrict__ cnt_f,
                      float* __restrict__ dis_s, float* __restrict__ dis_f, int N) {
  int i = blockIdx.x * blockDim.x + threadIdx.x;
  if (i < N) {
    unsigned long long p = pk_s[i];
    cnt_s[i] = (int)(p >> 40);
    dis_s[i] = rsqrtf(1.0f + (float)((double)(p & 0xFFFFFFFFFFULL) * (1.0 / (double)FIXS)));
    p = pk_f[i];
    cnt_f[i] = (int)(p >> 40);
    dis_f[i] = rsqrtf(1.0f + (float)((double)(p & 0xFFFFFFFFFFULL) * (1.0 / (double)FIXS)));
  }
}

// ---------- parallel exclusive scan (3 stages) ----------
__global__ void k_scan1(const int* __restrict__ cnt_s, const int* __restrict__ cnt_f,
                        int* __restrict__ rp_s, int* __restrict__ rp_f,
                        int* __restrict__ bsum, int N, int nb) {
  const int* cnt = blockIdx.y ? cnt_f : cnt_s;
  int*       rp  = blockIdx.y ? rp_f  : rp_s;
  __shared__ int buf[THREADS];
  int i = blockIdx.x * THREADS + threadIdx.x;
  int v = (i < N) ? cnt[i] : 0;
  buf[threadIdx.x] = v;
  __syncthreads();
  #pragma unroll
  for (int off = 1; off < THREADS; off <<= 1) {
    int t = (threadIdx.x >= off) ? buf[threadIdx.x - off] : 0;
    __syncthreads();
    buf[threadIdx.x] += t;
    __syncthreads();
  }
  if (i < N) rp[i] = buf[threadIdx.x] - v;          // block-local exclusive
  if (threadIdx.x == THREADS - 1) bsum[blockIdx.y * nb + blockIdx.x] = buf[THREADS - 1];
}

__global__ void k_scan2(int* __restrict__ bsum, int nb) {
  __shared__ int buf[THREADS];
  int* b = bsum + blockIdx.x * nb;
  int v = (threadIdx.x < nb) ? b[threadIdx.x] : 0;
  buf[threadIdx.x] = v;
  __syncthreads();
  #pragma unroll
  for (int off = 1; off < THREADS; off <<= 1) {
    int t = (threadIdx.x >= off) ? buf[threadIdx.x - off] : 0;
    __syncthreads();
    buf[threadIdx.x] += t;
    __syncthreads();
  }
  if (threadIdx.x < nb) b[threadIdx.x] = buf[threadIdx.x] - v;   // exclusive
}

__global__ void k_scan3(int* __restrict__ rp_s, int* __restrict__ rp_f,
                        int* __restrict__ cur_s, int* __restrict__ cur_f,
                        const int* __restrict__ bsum, int N, int nb, int E) {
  int* rp  = blockIdx.y ? rp_f  : rp_s;
  int* cur = blockIdx.y ? cur_f : cur_s;
  const int* bs = bsum + blockIdx.y * nb;
  int i = blockIdx.x * THREADS + threadIdx.x;
  if (i < N) {
    int e = rp[i] + bs[blockIdx.x];
    rp[i]  = e;
    cur[i] = e;
  }
  if (i == 0) rp[N] = E;
}

// both graphs; store (src, norm-weight) as one int2
__global__ void k_scatter2(const int* __restrict__ ei_s, const float* __restrict__ w_s,
                           const int* __restrict__ ei_f, const float* __restrict__ w_f,
                           const float* __restrict__ dis_s, const float* __restrict__ dis_f,
                           int* __restrict__ cur_s, int* __restrict__ cur_f,
                           int2* __restrict__ ed_s, int2* __restrict__ ed_f, int E) {
  const int*   ei  = blockIdx.y ? ei_f  : ei_s;
  const float* w   = blockIdx.y ? w_f   : w_s;
  const float* dis = blockIdx.y ? dis_f : dis_s;
  int*         cur = blockIdx.y ? cur_f : cur_s;
  int2*        ed  = blockIdx.y ? ed_f  : ed_s;
  int e = blockIdx.x * blockDim.x + threadIdx.x;
  if (e < E) {
    int r = ei[e];
    int c = ei[E + e];
    int pos = atomicAdd(&cur[c], 1);
    ed[pos] = make_int2(r, __float_as_int(dis[r] * w[e] * dis[c]));
  }
}

// ---------- cast x (f32) -> bf16 ----------
__global__ void k_cast(const float* __restrict__ in, unsigned short* __restrict__ out, int total4) {
  for (int i = blockIdx.x * blockDim.x + threadIdx.x; i < total4; i += gridDim.x * blockDim.x) {
    float4 v = ((const float4*)in)[i];
    ushort4 o;
    o.x = f2bf(v.x); o.y = f2bf(v.y); o.z = f2bf(v.z); o.w = f2bf(v.w);
    ((ushort4*)out)[i] = o;
  }
}

// ---------- MFMA GEMM: C(bf16) = A(N x 128, bf16) @ W(128 x 128, f32) ----------
__global__ __launch_bounds__(THREADS) void k_gemm_mfma(
    const unsigned short* __restrict__ A,
    const float* __restrict__ B0, const float* __restrict__ B1,
    unsigned short* __restrict__ C0, unsigned short* __restrict__ C1, int N) {
  const float*    W = blockIdx.y ? B1 : B0;
  unsigned short* C = blockIdx.y ? C1 : C0;
  __shared__ unsigned short Wt[128 * 128];   // 32 KiB, [n][k] swizzled
  int tid = threadIdx.x;
  #pragma unroll
  for (int p = 0; p < 32; ++p) {             // 128 n * 64 kpairs / 256 thr
    int idx = p * 256 + tid;
    int kp = idx & 63, n = idx >> 6;         // k = 2*kp
    float w0 = W[(2 * kp) * 128 + n];
    float w1 = W[(2 * kp + 1) * 128 + n];
    unsigned pk = (unsigned)f2bf(w0) | ((unsigned)f2bf(w1) << 16);
    unsigned byte = (unsigned)(n * 256 + kp * 4) ^ ((unsigned)(n & 7) << 4);
    *(unsigned*)((char*)Wt + byte) = pk;
  }
  __syncthreads();

  int wid = tid >> 6, lane = tid & 63;
  int row0 = blockIdx.x * 64 + wid * 16;
  int rowA = row0 + (lane & 15); if (rowA > N - 1) rowA = N - 1;   // clamp; store guarded
  const unsigned short* arow = A + (size_t)rowA * 128;
  int kg = lane >> 4;                        // 0..3

  f32x4 acc[8];
  #pragma unroll
  for (int nt = 0; nt < 8; ++nt) acc[nt] = (f32x4){0.f, 0.f, 0.f, 0.f};

  #pragma unroll
  for (int ks = 0; ks < 4; ++ks) {
    s16x8 afrag = *(const s16x8*)(arow + ks * 32 + kg * 8);
    #pragma unroll
    for (int nt = 0; nt < 8; ++nt) {
      int col = nt * 16 + (lane & 15);
      unsigned byte = (unsigned)(col * 256 + (ks * 32 + kg * 8) * 2) ^ ((unsigned)(col & 7) << 4);
      s16x8 bfrag = *(const s16x8*)((char*)Wt + byte);
      acc[nt] = __builtin_amdgcn_mfma_f32_16x16x32_bf16(afrag, bfrag, acc[nt], 0, 0, 0);
    }
  }
  // C/D layout (m89): col = lane&15, row = (lane>>4)*4 + reg
  #pragma unroll
  for (int nt = 0; nt < 8; ++nt) {
    int col = nt * 16 + (lane & 15);
    #pragma unroll
    for (int r = 0; r < 4; ++r) {
      int row = row0 + kg * 4 + r;
      if (row < N) C[(size_t)row * 128 + col] = f2bf(acc[nt][r]);
    }
  }
}

// ---------- aggregation over bf16 t-buffers ----------
__global__ __launch_bounds__(THREADS) void k_gather(
    const unsigned short* __restrict__ t_sc, const unsigned short* __restrict__ t_fc,
    const int* __restrict__ rp_s, const int2* __restrict__ ed_s,
    const int* __restrict__ rp_f, const int2* __restrict__ ed_f,
    const float* __restrict__ dis_s, const float* __restrict__ dis_f,
    float* __restrict__ agg, int N) {
  int gw     = (blockIdx.x * blockDim.x + threadIdx.x) >> 6;
  int lane   = threadIdx.x & 63;
  int nwaves = (gridDim.x * blockDim.x) >> 6;
  for (int v = gw; v < N; v += nwaves) {
    float ds = dis_s[v], df = dis_f[v];
    float inv_s = ds * ds, inv_f = df * df;   // self-loop norm = 1/deg
    unsigned a = ((const unsigned*)(t_sc + (size_t)v * 128))[lane];
    unsigned b = ((const unsigned*)(t_fc + (size_t)v * 128))[lane];
    float ax = bf2f((unsigned short)a) * inv_s + bf2f((unsigned short)b) * inv_f;
    float ay = bf2f((unsigned short)(a >> 16)) * inv_s + bf2f((unsigned short)(b >> 16)) * inv_f;

    #pragma unroll 1
    for (int g = 0; g < 2; ++g) {
      const int*            rp = g ? rp_f : rp_s;
      const int2*           ed = g ? ed_f : ed_s;
      const unsigned short* t  = g ? t_fc : t_sc;
      int e0 = rp[v], e1 = rp[v + 1];
      int e = e0;
      for (; e + 7 < e1; e += 8) {          // 8 independent row loads in flight
        int2 p0 = ed[e],     p1 = ed[e + 1], p2 = ed[e + 2], p3 = ed[e + 3];
        int2 p4 = ed[e + 4], p5 = ed[e + 5], p6 = ed[e + 6], p7 = ed[e + 7];
        unsigned r0 = ((const unsigned*)(t + (size_t)p0.x * 128))[lane];
        unsigned r1 = ((const unsigned*)(t + (size_t)p1.x * 128))[lane];
        unsigned r2 = ((const unsigned*)(t + (size_t)p2.x * 128))[lane];
        unsigned r3 = ((const unsigned*)(t + (size_t)p3.x * 128))[lane];
        unsigned r4 = ((const unsigned*)(t + (size_t)p4.x * 128))[lane];
        unsigned r5 = ((const unsigned*)(t + (size_t)p5.x * 128))[lane];
        unsigned r6 = ((const unsigned*)(t + (size_t)p6.x * 128))[lane];
        unsigned r7 = ((const unsigned*)(t + (size_t)p7.x * 128))[lane];
        float w0 = __int_as_float(p0.y), w1 = __int_as_float(p1.y);
        float w2 = __int_as_float(p2.y), w3 = __int_as_float(p3.y);
        float w4 = __int_as_float(p4.y), w5 = __int_as_float(p5.y);
        float w6 = __int_as_float(p6.y), w7 = __int_as_float(p7.y);
        ax = fmaf(bf2f((unsigned short)r0), w0, ax); ay = fmaf(bf2f((unsigned short)(r0 >> 16)), w0, ay);
        ax = fmaf(bf2f((unsigned short)r1), w1, ax); ay = fmaf(bf2f((unsigned short)(r1 >> 16)), w1, ay);
        ax = fmaf(bf2f((unsigned short)r2), w2, ax); ay = fmaf(bf2f((unsigned short)(r2 >> 16)), w2, ay);
        ax = fmaf(bf2f((unsigned short)r3), w3, ax); ay = fmaf(bf2f((unsigned short)(r3 >> 16)), w3, ay);
        ax = fmaf(bf2f((unsigned short)r4), w4, ax); ay = fmaf(bf2f((unsigned short)(r4 >> 16)), w4, ay);
        ax = fmaf(bf2f((unsigned short)r5), w5, ax); ay = fmaf(bf2f((unsigned short)(r5 >> 16)), w5, ay);
        ax = fmaf(bf2f((unsigned short)r6), w6, ax); ay = fmaf(bf2f((unsigned short)(r6 >> 16)), w6, ay);
        ax = fmaf(bf2f((unsigned short)r7), w7, ax); ay = fmaf(bf2f((unsigned short)(r7 >> 16)), w7, ay);
      }
      for (; e + 1 < e1; e += 2) {
        int2 p0 = ed[e], p1 = ed[e + 1];
        unsigned r0 = ((const unsigned*)(t + (size_t)p0.x * 128))[lane];
        unsigned r1 = ((const unsigned*)(t + (size_t)p1.x * 128))[lane];
        float w0 = __int_as_float(p0.y), w1 = __int_as_float(p1.y);
        ax = fmaf(bf2f((unsigned short)r0), w0, ax); ay = fmaf(bf2f((unsigned short)(r0 >> 16)), w0, ay);
        ax = fmaf(bf2f((unsigned short)r1), w1, ax); ay = fmaf(bf2f((unsigned short)(r1 >> 16)), w1, ay);
      }
      if (e < e1) {
        int2 p0 = ed[e];
        unsigned r0 = ((const unsigned*)(t + (size_t)p0.x * 128))[lane];
        float w0 = __int_as_float(p0.y);
        ax = fmaf(bf2f((unsigned short)r0), w0, ax);
        ay = fmaf(bf2f((unsigned short)(r0 >> 16)), w0, ay);
      }
    }
    ((float2*)(agg + (size_t)v * 128))[lane] = make_float2(ax, ay);
  }
}

// ---------- BN stats: per-block partials (no atomics) + reduce ----------
#define SBLK 256
__global__ void k_stats(const float* __restrict__ agg, double* __restrict__ pb, int N) {
  __shared__ double sb[THREADS], qb[THREADS];
  int col  = threadIdx.x & 127;
  int half = threadIdx.x >> 7;
  double s = 0, q = 0;
  for (int r = blockIdx.x * 2 + half; r < N; r += gridDim.x * 2) {
    float v = agg[(size_t)r * 128 + col];
    s += v; q += (double)v * v;
  }
  sb[threadIdx.x] = s; qb[threadIdx.x] = q;
  __syncthreads();
  if (half == 0) {
    pb[(size_t)blockIdx.x * 256 + col]       = sb[threadIdx.x] + sb[threadIdx.x + 128];
    pb[(size_t)blockIdx.x * 256 + 128 + col] = qb[threadIdx.x] + qb[threadIdx.x + 128];
  }
}

__global__ void k_stats2(const double* __restrict__ pb, double* __restrict__ stats) {
  int t = threadIdx.x;   // 256 threads: col = t&127, kind = t>>7
  double s = 0;
  for (int b = 0; b < SBLK; ++b) s += pb[(size_t)b * 256 + t];
  stats[t] = s;
}

// last==0: write bf16 h for next layer's GEMM. last==1: write f32 d_out.
__global__ void k_bn(const float* __restrict__ agg, const double* __restrict__ stats,
                     const float* __restrict__ gamma, const float* __restrict__ beta,
                     unsigned short* __restrict__ outb, float* __restrict__ outf,
                     int N, int last) {
  int total = N * 128;
  double invN = 1.0 / (double)N;
  for (int i = blockIdx.x * blockDim.x + threadIdx.x; i < total; i += gridDim.x * blockDim.x) {
    int c = i & 127;
    double m   = stats[c] * invN;
    double var = stats[128 + c] * invN - m * m;
    float scale = gamma[c] * rsqrtf((float)var + 1e-5f);
    float shift = beta[c] - (float)m * scale;
    float v = fmaf(agg[i], scale, shift);
    v = v > 0.f ? v : 0.f;
    if (last) outf[i] = v;
    else      outb[i] = f2bf(v);
  }
}

extern "C" void kernel_launch(void* const* d_in, const int* in_sizes, int n_in,
                              void* d_out, int out_size, void* d_ws, size_t ws_size,
                              hipStream_t stream) {
  const float* x     = (const float*)d_in[0];
  const int*   ei_s  = (const int*)d_in[1];
  const float* w_s   = (const float*)d_in[2];
  const int*   ei_f  = (const int*)d_in[3];
  const float* w_f   = (const float*)d_in[4];
  const float* W_s   = (const float*)d_in[5];
  const float* W_f   = (const float*)d_in[7];
  const float* gamma = (const float*)d_in[9];
  const float* beta  = (const float*)d_in[10];
  float* out = (float*)d_out;

  const int N = in_sizes[0] / 128;
  const int E = in_sizes[2];
  const int L = in_sizes[5] / (128 * 128);

  char* ws = (char*)d_ws;
  size_t off = 0;
  auto alloc = [&](size_t bytes) -> void* {
    void* p = (void*)(ws + off);
    off += (bytes + 255) & ~(size_t)255;
    return p;
  };
  double* stats = (double*)alloc(256 * sizeof(double));
  double* pb    = (double*)alloc((size_t)SBLK * 256 * sizeof(double));
  unsigned short* t_sc = (unsigned short*)alloc((size_t)N * 128 * 2);
  unsigned short* t_fc = (unsigned short*)alloc((size_t)N * 128 * 2);
  unsigned short* hb   = (unsigned short*)alloc((size_t)N * 128 * 2);
  float* agg   = (float*)alloc((size_t)N * 128 * 4);
  float* dis_s = (float*)alloc((size_t)N * 4);
  float* dis_f = (float*)alloc((size_t)N * 4);
  int*   rp_s  = (int*)alloc((size_t)(N + 1) * 4);
  int*   rp_f  = (int*)alloc((size_t)(N + 1) * 4);
  int*   cur_s = (int*)alloc((size_t)N * 4);
  int*   cur_f = (int*)alloc((size_t)N * 4);
  unsigned long long* pk_s = (unsigned long long*)alloc((size_t)N * 8);
  unsigned long long* pk_f = (unsigned long long*)alloc((size_t)N * 8);
  int2* ed_s = (int2*)alloc((size_t)E * 8);
  int2* ed_f = (int2*)alloc((size_t)E * 8);

  int nb_n = (N + THREADS - 1) / THREADS;           // 196
  int nb_e = (E + THREADS - 1) / THREADS;           // 2500
  int* bsum = (int*)alloc((size_t)2 * nb_n * 4);

  dim3 ge(nb_e, 2), gn(nb_n, 2);

  // CSR + degree build (layer-invariant)
  k_init<<<nb_n, THREADS, 0, stream>>>(pk_s, pk_f, N);
  k_count2<<<ge, THREADS, 0, stream>>>(ei_s + E, w_s, ei_f + E, w_f, pk_s, pk_f, E);
  k_pre<<<nb_n, THREADS, 0, stream>>>(pk_s, pk_f, cur_s, cur_f, dis_s, dis_f, N);
  k_scan1<<<gn, THREADS, 0, stream>>>(cur_s, cur_f, rp_s, rp_f, bsum, N, nb_n);
  k_scan2<<<2, THREADS, 0, stream>>>(bsum, nb_n);
  k_scan3<<<gn, THREADS, 0, stream>>>(rp_s, rp_f, cur_s, cur_f, bsum, N, nb_n, E);
  k_scatter2<<<ge, THREADS, 0, stream>>>(ei_s, w_s, ei_f, w_f, dis_s, dis_f,
                                         cur_s, cur_f, ed_s, ed_f, E);

  k_cast<<<1024, THREADS, 0, stream>>>(x, hb, N * 128 / 4);

  for (int l = 0; l < L; ++l) {
    dim3 gg((N + 63) / 64, 2);
    k_gemm_mfma<<<gg, THREADS, 0, stream>>>(hb, W_s + (size_t)l * 128 * 128,
                                            W_f + (size_t)l * 128 * 128, t_sc, t_fc, N);
    k_gather<<<2048, THREADS, 0, stream>>>(t_sc, t_fc, rp_s, ed_s, rp_f, ed_f,
                                           dis_s, dis_f, agg, N);
    k_stats<<<SBLK, THREADS, 0, stream>>>(agg, pb, N);
    k_stats2<<<1, 256, 0, stream>>>(pb, stats);
    k_bn<<<2048, THREADS, 0, stream>>>(agg, stats, gamma + l * 128, beta + l * 128,
                                       hb, out, N, (l == L - 1) ? 1 : 0);
  }
}

// Round 9
// 403.323 us; speedup vs baseline: 2.2570x; 1.1929x over previous
//
#include <hip/hip_runtime.h>
#include <hip/hip_bf16.h>

#define THREADS 256
#define FIXS 67108864.0f   // 2^26 fixed-point scale for weight sums

typedef __attribute__((ext_vector_type(8))) short s16x8;   // 8 bf16 = 4 VGPR
typedef __attribute__((ext_vector_type(4))) float f32x4;

// bf16 helpers (RNE)
static __device__ __forceinline__ unsigned short f2bf(float f) {
  union { float f; unsigned u; } v; v.f = f;
  unsigned r = (v.u + 0x7FFF + ((v.u >> 16) & 1)) >> 16;
  return (unsigned short)r;
}
static __device__ __forceinline__ float bf2f(unsigned short h) {
  union { unsigned u; float f; } v; v.u = ((unsigned)h) << 16;
  return v.f;
}

// ---------- CSR build ----------
__global__ void k_init(unsigned long long* pk_s, unsigned long long* pk_f, int N) {
  for (int i = blockIdx.x * blockDim.x + threadIdx.x; i < N; i += gridDim.x * blockDim.x) {
    pk_s[i] = 0ULL; pk_f[i] = 0ULL;
  }
}

// one u64 atomic per edge: count in high 24 bits, Σw in 2^-26 fixed point low 40 bits
__global__ void k_count2(const int* __restrict__ col_s, const float* __restrict__ w_s,
                         const int* __restrict__ col_f, const float* __restrict__ w_f,
                         unsigned long long* pk_s, unsigned long long* pk_f, int E) {
  const int*          col = blockIdx.y ? col_f : col_s;
  const float*        w   = blockIdx.y ? w_f  : w_s;
  unsigned long long* pk  = blockIdx.y ? pk_f : pk_s;
  int e = blockIdx.x * blockDim.x + threadIdx.x;
  if (e < E) {
    unsigned long long fx = (unsigned long long)(w[e] * FIXS + 0.5f);
    atomicAdd(&pk[col[e]], (1ULL << 40) | fx);
  }
}

// unpack: cnt (for scan) + dis = rsqrt(1 + Σw)
__global__ void k_pre(const unsigned long long* __restrict__ pk_s,
                      const unsigned long long* __restrict__ pk_f,
                      int* __restrict__ cnt_s, int* __restrict__ cnt_f,
                      float* __restrict__ dis_s, float* __restrict__ dis_f, int N) {
  int i = blockIdx.x * blockDim.x + threadIdx.x;
  if (i < N) {
    unsigned long long p = pk_s[i];
    cnt_s[i] = (int)(p >> 40);
    dis_s[i] = rsqrtf(1.0f + (float)((double)(p & 0xFFFFFFFFFFULL) * (1.0 / (double)FIXS)));
    p = pk_f[i];
    cnt_f[i] = (int)(p >> 40);
    dis_f[i] = rsqrtf(1.0f + (float)((double)(p & 0xFFFFFFFFFFULL) * (1.0 / (double)FIXS)));
  }
}

// ---------- parallel exclusive scan (3 stages) ----------
__global__ void k_scan1(const int* __restrict__ cnt_s, const int* __restrict__ cnt_f,
                        int* __restrict__ rp_s, int* __restrict__ rp_f,
                        int* __restrict__ bsum, int N, int nb) {
  const int* cnt = blockIdx.y ? cnt_f : cnt_s;
  int*       rp  = blockIdx.y ? rp_f  : rp_s;
  __shared__ int buf[THREADS];
  int i = blockIdx.x * THREADS + threadIdx.x;
  int v = (i < N) ? cnt[i] : 0;
  buf[threadIdx.x] = v;
  __syncthreads();
  #pragma unroll
  for (int off = 1; off < THREADS; off <<= 1) {
    int t = (threadIdx.x >= off) ? buf[threadIdx.x - off] : 0;
    __syncthreads();
    buf[threadIdx.x] += t;
    __syncthreads();
  }
  if (i < N) rp[i] = buf[threadIdx.x] - v;          // block-local exclusive
  if (threadIdx.x == THREADS - 1) bsum[blockIdx.y * nb + blockIdx.x] = buf[THREADS - 1];
}

__global__ void k_scan2(int* __restrict__ bsum, int nb) {
  __shared__ int buf[THREADS];
  int* b = bsum + blockIdx.x * nb;
  int v = (threadIdx.x < nb) ? b[threadIdx.x] : 0;
  buf[threadIdx.x] = v;
  __syncthreads();
  #pragma unroll
  for (int off = 1; off < THREADS; off <<= 1) {
    int t = (threadIdx.x >= off) ? buf[threadIdx.x - off] : 0;
    __syncthreads();
    buf[threadIdx.x] += t;
    __syncthreads();
  }
  if (threadIdx.x < nb) b[threadIdx.x] = buf[threadIdx.x] - v;   // exclusive
}

__global__ void k_scan3(int* __restrict__ rp_s, int* __restrict__ rp_f,
                        int* __restrict__ cur_s, int* __restrict__ cur_f,
                        const int* __restrict__ bsum, int N, int nb, int E) {
  int* rp  = blockIdx.y ? rp_f  : rp_s;
  int* cur = blockIdx.y ? cur_f : cur_s;
  const int* bs = bsum + blockIdx.y * nb;
  int i = blockIdx.x * THREADS + threadIdx.x;
  if (i < N) {
    int e = rp[i] + bs[blockIdx.x];
    rp[i]  = e;
    cur[i] = e;
  }
  if (i == 0) rp[N] = E;
}

// both graphs; store (src, norm-weight) as one int2
__global__ void k_scatter2(const int* __restrict__ ei_s, const float* __restrict__ w_s,
                           const int* __restrict__ ei_f, const float* __restrict__ w_f,
                           const float* __restrict__ dis_s, const float* __restrict__ dis_f,
                           int* __restrict__ cur_s, int* __restrict__ cur_f,
                           int2* __restrict__ ed_s, int2* __restrict__ ed_f, int E) {
  const int*   ei  = blockIdx.y ? ei_f  : ei_s;
  const float* w   = blockIdx.y ? w_f   : w_s;
  const float* dis = blockIdx.y ? dis_f : dis_s;
  int*         cur = blockIdx.y ? cur_f : cur_s;
  int2*        ed  = blockIdx.y ? ed_f  : ed_s;
  int e = blockIdx.x * blockDim.x + threadIdx.x;
  if (e < E) {
    int r = ei[e];
    int c = ei[E + e];
    int pos = atomicAdd(&cur[c], 1);
    ed[pos] = make_int2(r, __float_as_int(dis[r] * w[e] * dis[c]));
  }
}

// ---------- cast x (f32) -> bf16 ----------
__global__ void k_cast(const float* __restrict__ in, unsigned short* __restrict__ out, int total4) {
  for (int i = blockIdx.x * blockDim.x + threadIdx.x; i < total4; i += gridDim.x * blockDim.x) {
    float4 v = ((const float4*)in)[i];
    ushort4 o;
    o.x = f2bf(v.x); o.y = f2bf(v.y); o.z = f2bf(v.z); o.w = f2bf(v.w);
    ((ushort4*)out)[i] = o;
  }
}

// ---------- one-time weight prep: f32 [k][n] -> bf16 transposed [n][k], XOR-swizzled ----------
// Output is the exact 32 KiB byte image the GEMM wants in LDS.
__global__ void k_prew(const float* __restrict__ W_s, const float* __restrict__ W_f,
                       unsigned* __restrict__ Wsw) {
  int m = blockIdx.x;                 // 0..2L-1: matrix id (l = m>>1, branch = m&1)
  const float* W = ((m & 1) ? W_f : W_s) + (size_t)(m >> 1) * 128 * 128;
  unsigned* dst = Wsw + (size_t)m * 8192;
  int tid = threadIdx.x;
  #pragma unroll
  for (int p = 0; p < 32; ++p) {
    int idx = p * 256 + tid;          // dword index
    int kp = idx & 63, n = idx >> 6;  // k = 2*kp
    float w0 = W[(2 * kp) * 128 + n];
    float w1 = W[(2 * kp + 1) * 128 + n];
    unsigned pk = (unsigned)f2bf(w0) | ((unsigned)f2bf(w1) << 16);
    unsigned byte = (unsigned)(n * 256 + kp * 4) ^ ((unsigned)(n & 7) << 4);
    *(unsigned*)((char*)dst + byte) = pk;
  }
}

// ---------- MFMA GEMM: C(bf16) = A(N x 128, bf16) @ W (pre-swizzled bf16) ----------
// 256 thr = 4 waves; 128 rows/block (2 row-tiles of 16 per wave); staging = linear float4 copy.
__global__ __launch_bounds__(THREADS) void k_gemm_mfma(
    const unsigned short* __restrict__ A,
    const unsigned* __restrict__ Wsw,            // 2 matrices for this layer
    unsigned short* __restrict__ C0, unsigned short* __restrict__ C1, int N) {
  const unsigned* Wm = Wsw + (size_t)blockIdx.y * 8192;
  unsigned short* C  = blockIdx.y ? C1 : C0;
  __shared__ unsigned Wt[8192];                  // 32 KiB
  int tid = threadIdx.x;
  #pragma unroll
  for (int i = 0; i < 8; ++i)
    ((float4*)Wt)[i * 256 + tid] = ((const float4*)Wm)[i * 256 + tid];
  __syncthreads();

  int wid = tid >> 6, lane = tid & 63;
  int kg = lane >> 4;                            // 0..3
  int rbase = blockIdx.x * 128 + wid * 32;       // wave covers rows [rbase, rbase+32)
  const unsigned short* arow[2];
  #pragma unroll
  for (int rt = 0; rt < 2; ++rt) {
    int r = rbase + rt * 16 + (lane & 15); if (r > N - 1) r = N - 1;   // clamp; store guarded
    arow[rt] = A + (size_t)r * 128;
  }

  f32x4 acc[2][8];
  #pragma unroll
  for (int rt = 0; rt < 2; ++rt)
    #pragma unroll
    for (int nt = 0; nt < 8; ++nt) acc[rt][nt] = (f32x4){0.f, 0.f, 0.f, 0.f};

  #pragma unroll
  for (int ks = 0; ks < 4; ++ks) {
    s16x8 af0 = *(const s16x8*)(arow[0] + ks * 32 + kg * 8);
    s16x8 af1 = *(const s16x8*)(arow[1] + ks * 32 + kg * 8);
    #pragma unroll
    for (int nt = 0; nt < 8; ++nt) {
      int col = nt * 16 + (lane & 15);
      unsigned byte = (unsigned)(col * 256 + (ks * 32 + kg * 8) * 2) ^ ((unsigned)(col & 7) << 4);
      s16x8 bfrag = *(const s16x8*)((char*)Wt + byte);
      acc[0][nt] = __builtin_amdgcn_mfma_f32_16x16x32_bf16(af0, bfrag, acc[0][nt], 0, 0, 0);
      acc[1][nt] = __builtin_amdgcn_mfma_f32_16x16x32_bf16(af1, bfrag, acc[1][nt], 0, 0, 0);
    }
  }
  // C/D layout (m89): col = lane&15, row = (lane>>4)*4 + reg
  #pragma unroll
  for (int rt = 0; rt < 2; ++rt) {
    #pragma unroll
    for (int nt = 0; nt < 8; ++nt) {
      int col = nt * 16 + (lane & 15);
      #pragma unroll
      for (int r = 0; r < 4; ++r) {
        int row = rbase + rt * 16 + kg * 4 + r;
        if (row < N) C[(size_t)row * 128 + col] = f2bf(acc[rt][nt][r]);
      }
    }
  }
}

// ---------- aggregation over bf16 t-buffers ----------
__global__ __launch_bounds__(THREADS) void k_gather(
    const unsigned short* __restrict__ t_sc, const unsigned short* __restrict__ t_fc,
    const int* __restrict__ rp_s, const int2* __restrict__ ed_s,
    const int* __restrict__ rp_f, const int2* __restrict__ ed_f,
    const float* __restrict__ dis_s, const float* __restrict__ dis_f,
    float* __restrict__ agg, int N) {
  int gw     = (blockIdx.x * blockDim.x + threadIdx.x) >> 6;
  int lane   = threadIdx.x & 63;
  int nwaves = (gridDim.x * blockDim.x) >> 6;
  for (int v = gw; v < N; v += nwaves) {
    float ds = dis_s[v], df = dis_f[v];
    float inv_s = ds * ds, inv_f = df * df;   // self-loop norm = 1/deg
    unsigned a = ((const unsigned*)(t_sc + (size_t)v * 128))[lane];
    unsigned b = ((const unsigned*)(t_fc + (size_t)v * 128))[lane];
    float ax = bf2f((unsigned short)a) * inv_s + bf2f((unsigned short)b) * inv_f;
    float ay = bf2f((unsigned short)(a >> 16)) * inv_s + bf2f((unsigned short)(b >> 16)) * inv_f;

    #pragma unroll 1
    for (int g = 0; g < 2; ++g) {
      const int*            rp = g ? rp_f : rp_s;
      const int2*           ed = g ? ed_f : ed_s;
      const unsigned short* t  = g ? t_fc : t_sc;
      int e0 = rp[v], e1 = rp[v + 1];
      int e = e0;
      for (; e + 7 < e1; e += 8) {          // 8 independent row loads in flight
        int2 p0 = ed[e],     p1 = ed[e + 1], p2 = ed[e + 2], p3 = ed[e + 3];
        int2 p4 = ed[e + 4], p5 = ed[e + 5], p6 = ed[e + 6], p7 = ed[e + 7];
        unsigned r0 = ((const unsigned*)(t + (size_t)p0.x * 128))[lane];
        unsigned r1 = ((const unsigned*)(t + (size_t)p1.x * 128))[lane];
        unsigned r2 = ((const unsigned*)(t + (size_t)p2.x * 128))[lane];
        unsigned r3 = ((const unsigned*)(t + (size_t)p3.x * 128))[lane];
        unsigned r4 = ((const unsigned*)(t + (size_t)p4.x * 128))[lane];
        unsigned r5 = ((const unsigned*)(t + (size_t)p5.x * 128))[lane];
        unsigned r6 = ((const unsigned*)(t + (size_t)p6.x * 128))[lane];
        unsigned r7 = ((const unsigned*)(t + (size_t)p7.x * 128))[lane];
        float w0 = __int_as_float(p0.y), w1 = __int_as_float(p1.y);
        float w2 = __int_as_float(p2.y), w3 = __int_as_float(p3.y);
        float w4 = __int_as_float(p4.y), w5 = __int_as_float(p5.y);
        float w6 = __int_as_float(p6.y), w7 = __int_as_float(p7.y);
        ax = fmaf(bf2f((unsigned short)r0), w0, ax); ay = fmaf(bf2f((unsigned short)(r0 >> 16)), w0, ay);
        ax = fmaf(bf2f((unsigned short)r1), w1, ax); ay = fmaf(bf2f((unsigned short)(r1 >> 16)), w1, ay);
        ax = fmaf(bf2f((unsigned short)r2), w2, ax); ay = fmaf(bf2f((unsigned short)(r2 >> 16)), w2, ay);
        ax = fmaf(bf2f((unsigned short)r3), w3, ax); ay = fmaf(bf2f((unsigned short)(r3 >> 16)), w3, ay);
        ax = fmaf(bf2f((unsigned short)r4), w4, ax); ay = fmaf(bf2f((unsigned short)(r4 >> 16)), w4, ay);
        ax = fmaf(bf2f((unsigned short)r5), w5, ax); ay = fmaf(bf2f((unsigned short)(r5 >> 16)), w5, ay);
        ax = fmaf(bf2f((unsigned short)r6), w6, ax); ay = fmaf(bf2f((unsigned short)(r6 >> 16)), w6, ay);
        ax = fmaf(bf2f((unsigned short)r7), w7, ax); ay = fmaf(bf2f((unsigned short)(r7 >> 16)), w7, ay);
      }
      for (; e + 1 < e1; e += 2) {
        int2 p0 = ed[e], p1 = ed[e + 1];
        unsigned r0 = ((const unsigned*)(t + (size_t)p0.x * 128))[lane];
        unsigned r1 = ((const unsigned*)(t + (size_t)p1.x * 128))[lane];
        float w0 = __int_as_float(p0.y), w1 = __int_as_float(p1.y);
        ax = fmaf(bf2f((unsigned short)r0), w0, ax); ay = fmaf(bf2f((unsigned short)(r0 >> 16)), w0, ay);
        ax = fmaf(bf2f((unsigned short)r1), w1, ax); ay = fmaf(bf2f((unsigned short)(r1 >> 16)), w1, ay);
      }
      if (e < e1) {
        int2 p0 = ed[e];
        unsigned r0 = ((const unsigned*)(t + (size_t)p0.x * 128))[lane];
        float w0 = __int_as_float(p0.y);
        ax = fmaf(bf2f((unsigned short)r0), w0, ax);
        ay = fmaf(bf2f((unsigned short)(r0 >> 16)), w0, ay);
      }
    }
    ((float2*)(agg + (size_t)v * 128))[lane] = make_float2(ax, ay);
  }
}

// ---------- BN stats: per-block partials (no atomics) + reduce ----------
#define SBLK 256
__global__ void k_stats(const float* __restrict__ agg, double* __restrict__ pb, int N) {
  __shared__ double sb[THREADS], qb[THREADS];
  int col  = threadIdx.x & 127;
  int half = threadIdx.x >> 7;
  double s = 0, q = 0;
  for (int r = blockIdx.x * 2 + half; r < N; r += gridDim.x * 2) {
    float v = agg[(size_t)r * 128 + col];
    s += v; q += (double)v * v;
  }
  sb[threadIdx.x] = s; qb[threadIdx.x] = q;
  __syncthreads();
  if (half == 0) {
    pb[(size_t)blockIdx.x * 256 + col]       = sb[threadIdx.x] + sb[threadIdx.x + 128];
    pb[(size_t)blockIdx.x * 256 + 128 + col] = qb[threadIdx.x] + qb[threadIdx.x + 128];
  }
}

__global__ void k_stats2(const double* __restrict__ pb, double* __restrict__ stats) {
  int t = threadIdx.x;   // 256 threads: col = t&127, kind = t>>7
  double s = 0;
  for (int b = 0; b < SBLK; ++b) s += pb[(size_t)b * 256 + t];
  stats[t] = s;
}

// last==0: write bf16 h for next layer's GEMM. last==1: write f32 d_out.
__global__ void k_bn(const float* __restrict__ agg, const double* __restrict__ stats,
                     const float* __restrict__ gamma, const float* __restrict__ beta,
                     unsigned short* __restrict__ outb, float* __restrict__ outf,
                     int N, int last) {
  int total = N * 128;
  double invN = 1.0 / (double)N;
  for (int i = blockIdx.x * blockDim.x + threadIdx.x; i < total; i += gridDim.x * blockDim.x) {
    int c = i & 127;
    double m   = stats[c] * invN;
    double var = stats[128 + c] * invN - m * m;
    float scale = gamma[c] * rsqrtf((float)var + 1e-5f);
    float shift = beta[c] - (float)m * scale;
    float v = fmaf(agg[i], scale, shift);
    v = v > 0.f ? v : 0.f;
    if (last) outf[i] = v;
    else      outb[i] = f2bf(v);
  }
}

extern "C" void kernel_launch(void* const* d_in, const int* in_sizes, int n_in,
                              void* d_out, int out_size, void* d_ws, size_t ws_size,
                              hipStream_t stream) {
  const float* x     = (const float*)d_in[0];
  const int*   ei_s  = (const int*)d_in[1];
  const float* w_s   = (const float*)d_in[2];
  const int*   ei_f  = (const int*)d_in[3];
  const float* w_f   = (const float*)d_in[4];
  const float* W_s   = (const float*)d_in[5];
  const float* W_f   = (const float*)d_in[7];
  const float* gamma = (const float*)d_in[9];
  const float* beta  = (const float*)d_in[10];
  float* out = (float*)d_out;

  const int N = in_sizes[0] / 128;
  const int E = in_sizes[2];
  const int L = in_sizes[5] / (128 * 128);

  char* ws = (char*)d_ws;
  size_t off = 0;
  auto alloc = [&](size_t bytes) -> void* {
    void* p = (void*)(ws + off);
    off += (bytes + 255) & ~(size_t)255;
    return p;
  };
  double* stats = (double*)alloc(256 * sizeof(double));
  double* pb    = (double*)alloc((size_t)SBLK * 256 * sizeof(double));
  unsigned* Wsw = (unsigned*)alloc((size_t)2 * L * 8192 * 4);
  unsigned short* t_sc = (unsigned short*)alloc((size_t)N * 128 * 2);
  unsigned short* t_fc = (unsigned short*)alloc((size_t)N * 128 * 2);
  unsigned short* hb   = (unsigned short*)alloc((size_t)N * 128 * 2);
  float* agg   = (float*)alloc((size_t)N * 128 * 4);
  float* dis_s = (float*)alloc((size_t)N * 4);
  float* dis_f = (float*)alloc((size_t)N * 4);
  int*   rp_s  = (int*)alloc((size_t)(N + 1) * 4);
  int*   rp_f  = (int*)alloc((size_t)(N + 1) * 4);
  int*   cur_s = (int*)alloc((size_t)N * 4);
  int*   cur_f = (int*)alloc((size_t)N * 4);
  unsigned long long* pk_s = (unsigned long long*)alloc((size_t)N * 8);
  unsigned long long* pk_f = (unsigned long long*)alloc((size_t)N * 8);
  int2* ed_s = (int2*)alloc((size_t)E * 8);
  int2* ed_f = (int2*)alloc((size_t)E * 8);

  int nb_n = (N + THREADS - 1) / THREADS;           // 196
  int nb_e = (E + THREADS - 1) / THREADS;           // 2500
  int* bsum = (int*)alloc((size_t)2 * nb_n * 4);

  dim3 ge(nb_e, 2), gn(nb_n, 2);

  // one-time weight prep + CSR/degree build (layer-invariant)
  k_prew<<<2 * L, THREADS, 0, stream>>>(W_s, W_f, Wsw);
  k_init<<<nb_n, THREADS, 0, stream>>>(pk_s, pk_f, N);
  k_count2<<<ge, THREADS, 0, stream>>>(ei_s + E, w_s, ei_f + E, w_f, pk_s, pk_f, E);
  k_pre<<<nb_n, THREADS, 0, stream>>>(pk_s, pk_f, cur_s, cur_f, dis_s, dis_f, N);
  k_scan1<<<gn, THREADS, 0, stream>>>(cur_s, cur_f, rp_s, rp_f, bsum, N, nb_n);
  k_scan2<<<2, THREADS, 0, stream>>>(bsum, nb_n);
  k_scan3<<<gn, THREADS, 0, stream>>>(rp_s, rp_f, cur_s, cur_f, bsum, N, nb_n, E);
  k_scatter2<<<ge, THREADS, 0, stream>>>(ei_s, w_s, ei_f, w_f, dis_s, dis_f,
                                         cur_s, cur_f, ed_s, ed_f, E);

  k_cast<<<1024, THREADS, 0, stream>>>(x, hb, N * 128 / 4);

  for (int l = 0; l < L; ++l) {
    dim3 gg((N + 127) / 128, 2);
    k_gemm_mfma<<<gg, THREADS, 0, stream>>>(hb, Wsw + (size_t)l * 2 * 8192,
                                            t_sc, t_fc, N);
    k_gather<<<2048, THREADS, 0, stream>>>(t_sc, t_fc, rp_s, ed_s, rp_f, ed_f,
                                           dis_s, dis_f, agg, N);
    k_stats<<<SBLK, THREADS, 0, stream>>>(agg, pb, N);
    k_stats2<<<1, 256, 0, stream>>>(pb, stats);
    k_bn<<<2048, THREADS, 0, stream>>>(agg, stats, gamma + l * 128, beta + l * 128,
                                       hb, out, N, (l == L - 1) ? 1 : 0);
  }
}